// Round 4
// baseline (3821.846 us; speedup 1.0000x reference)
//
#include <hip/hip_runtime.h>

typedef unsigned short u16;
typedef unsigned int   u32;
typedef __bf16 bf16x8 __attribute__((ext_vector_type(8)));
typedef float  f32x4  __attribute__((ext_vector_type(4)));
typedef u32    u32x4  __attribute__((ext_vector_type(4)));
typedef u16    u16x4  __attribute__((ext_vector_type(4)));

#define V_N   6890
#define V_PAD 6912

__device__ __forceinline__ float bf2f(u32 h) {
  union { u32 u; float f; } c; c.u = h << 16; return c.f;
}
__device__ __forceinline__ u16 f2bf(float f) {
  union { float f; u32 u; } c; c.f = f;
  return (u16)((c.u + 0x7fffu + ((c.u >> 16) & 1u)) >> 16);
}
__device__ __forceinline__ void gload_lds16(const void* g, void* l) {
  __builtin_amdgcn_global_load_lds((const __attribute__((address_space(1))) void*)g,
                                   (__attribute__((address_space(3))) void*)l, 16, 0, 0);
}

// ---- f32 -> bf16 (vec4) ----
__global__ void cvt_kernel(const float* __restrict__ in, u16* __restrict__ out, int total4) {
  int g = blockIdx.x * 256 + threadIdx.x;
  if (g >= total4) return;
  f32x4 v = *(const f32x4*)(in + (size_t)g * 4);
  u16x4 o; o.x = f2bf(v.x); o.y = f2bf(v.y); o.z = f2bf(v.z); o.w = f2bf(v.w);
  *(u16x4*)(out + (size_t)g * 4) = o;
}

// ---- build rotated templates, bf16, B^T layout ----
__global__ void trot_kernel(const float* __restrict__ T, u16* __restrict__ out,
                            int Tn, int Cc, int C4, int total) {
  int g = blockIdx.x * 256 + threadIdx.x;
  if (g >= total) return;
  int c4 = g % C4; int q = g / C4;
  int a = q & 7; q >>= 3;
  int r = q % 5; q /= 5;
  int t = q % Tn; int o = q / Tn;
  f32x4 s = *(const f32x4*)(T + (size_t)((t * 5 + r) * 8 + ((a - o + 8) & 7)) * Cc + c4 * 4);
  u16x4 d; d.x = f2bf(s.x); d.y = f2bf(s.y); d.z = f2bf(s.z); d.w = f2bf(s.w);
  *(u16x4*)(out + ((size_t)(o * Tn + t) * 40 + (r * 8 + a)) * Cc + c4 * 4) = d;
}

// ---- barycentric gather+interp ----
__global__ void interp_kernel(const u16* __restrict__ sig, int Cc, int C8,
                              const int* __restrict__ idx, const float* __restrict__ w,
                              u16* __restrict__ out, int v0, int Kl, int total) {
  int g = blockIdx.x * 256 + threadIdx.x;
  if (g >= total) return;
  int q = g / C8, c8 = g - q * C8;
  int vr = q / 40, ra = q - vr * 40;
  size_t ib = ((size_t)(v0 + vr) * 40 + ra) * 3;
  int i0 = idx[ib], i1 = idx[ib + 1], i2 = idx[ib + 2];
  float w0 = w[ib], w1 = w[ib + 1], w2 = w[ib + 2];
  u32x4 s0 = *(const u32x4*)(sig + (size_t)i0 * Cc + c8 * 8);
  u32x4 s1 = *(const u32x4*)(sig + (size_t)i1 * Cc + c8 * 8);
  u32x4 s2 = *(const u32x4*)(sig + (size_t)i2 * Cc + c8 * 8);
  u32x4 o;
#pragma unroll
  for (int j = 0; j < 4; ++j) {
    float lo = w0 * bf2f(s0[j] & 0xffffu) + w1 * bf2f(s1[j] & 0xffffu) + w2 * bf2f(s2[j] & 0xffffu);
    float hi = w0 * bf2f(s0[j] >> 16)     + w1 * bf2f(s1[j] >> 16)     + w2 * bf2f(s2[j] >> 16);
    o[j] = (u32)f2bf(lo) | ((u32)f2bf(hi) << 16);
  }
  *(u32x4*)(out + (size_t)vr * Kl + ra * Cc + c8 * 8) = o;
}

// ---- split-K reduce + relu(+bias) + angular max; optional split-bf16 (hi|lo) output ----
__global__ void amp_kernel(const float* __restrict__ Cin, size_t cstride, int nsplit,
                           const float* __restrict__ bias, u16* __restrict__ out,
                           int Tn, int ldo, int split, int total) {
  int g = blockIdx.x * 256 + threadIdx.x;
  if (g >= total) return;
  int t = g % Tn, v = g / Tn;
  const float* row = Cin + (size_t)v * (8 * Tn) + t;
  float acc[8];
#pragma unroll
  for (int o = 0; o < 8; ++o) acc[o] = row[(size_t)o * Tn];
  for (int s = 1; s < nsplit; ++s) {
    row += cstride;
#pragma unroll
    for (int o = 0; o < 8; ++o) acc[o] += row[(size_t)o * Tn];
  }
  float b = bias[t];
  float m = acc[0] + b;
#pragma unroll
  for (int o = 1; o < 8; ++o) m = fmaxf(m, acc[o] + b);
  m = fmaxf(m, 0.f);
  u16 hi = f2bf(m);
  out[(size_t)v * ldo + t] = hi;
  if (split) out[(size_t)v * ldo + Tn + t] = f2bf(m - bf2f(hi));
}

// ---- Wd [128][V] f32 -> WdT split-bf16 [V_PAD][256] (hi | lo along k) ----
__global__ void wdt_kernel(const float* __restrict__ Wd, u16* __restrict__ out, int total) {
  int g = blockIdx.x * 256 + threadIdx.x;
  if (g >= total) return;
  int k = g & 127, n = g >> 7;
  float v = (n < V_N) ? Wd[(size_t)k * V_N + n] : 0.f;
  u16 hi = f2bf(v);
  out[(size_t)n * 256 + k] = hi;
  out[(size_t)n * 256 + 128 + k] = f2bf(v - bf2f(hi));
}

// ---- 256x256 bf16 GEMM, BK=32, 8 waves (2Mx4N), double-buffered LDS (64 KiB -> 2 blocks/CU),
//      counted vmcnt(4) prefetch, bank-free swizzle (phys_chunk = logical ^ ((row>>1)&3)),
//      T5 setprio, split-K partials, bijective XCD block mapping. C = A * B^T (+bias). ----
__global__ __launch_bounds__(512, 4) void gemm256(
    const u16* __restrict__ A, int lda,
    const u16* __restrict__ B, int ldb,
    float* __restrict__ C, int ldc, size_t cstride,
    const float* __restrict__ bias,
    int Mvalid, int Nvalid, int kchunk, int Ktot,
    int ntm, int ntn) {
  __shared__ __align__(16) u16 lA[2][256 * 32];
  __shared__ __align__(16) u16 lB[2][256 * 32];
  const int tid = threadIdx.x;
  const int w = tid >> 6, l = tid & 63;

  // bijective XCD chunking (m204)
  const int nb = gridDim.x, bid = blockIdx.x;
  const int q = nb >> 3, r = nb & 7;
  const int xcd = bid & 7, ii = bid >> 3;
  const int vb = (xcd < r ? xcd * (q + 1) : r * (q + 1) + (xcd - r) * q) + ii;
  const int per = ntm * ntn;
  const int s = vb / per;
  const int rem = vb - s * per;
  const int tm = rem / ntn, tn = rem - tm * ntn;
  const int kb = s * kchunk;
  int ke = kb + kchunk; if (ke > Ktot) ke = Ktot;
  const int nt = (ke - kb + 31) >> 5;
  float* Cb = C + (size_t)s * cstride;

  const u16* Ab = A + (size_t)(tm * 256) * lda + kb;
  const u16* Bb = B + (size_t)(tn * 256) * ldb + kb;

  // staging: linear LDS dest (wave-uniform base + lane*16), pre-swizzled global col
  const int srow = tid >> 2;                                  // 0..127 (+i*128)
  const int scol = (((tid & 3) ^ ((tid >> 3) & 3)) << 3);     // elements
  u16* laBase = &lA[0][0];
  u16* lbBase = &lB[0][0];

  auto STAGE = [&](int buf, int k0) {
    const u16* ga = Ab + (size_t)srow * lda + k0 + scol;
    const u16* gb = Bb + (size_t)srow * ldb + k0 + scol;
    u16* la = laBase + buf * (256 * 32) + w * 512;   // +lane*8 u16 done by HW
    u16* lb = lbBase + buf * (256 * 32) + w * 512;
#pragma unroll
    for (int i = 0; i < 2; ++i) {
      gload_lds16(ga + (size_t)(i * 128) * lda, la + i * 4096);
      gload_lds16(gb + (size_t)(i * 128) * ldb, lb + i * 4096);
    }
  };

  f32x4 acc[8][4];
#pragma unroll
  for (int i = 0; i < 8; ++i)
#pragma unroll
    for (int j = 0; j < 4; ++j) acc[i][j] = (f32x4){0.f, 0.f, 0.f, 0.f};

  const int wm = w >> 2, wn = w & 3;
  const int aoffbase = (wm * 128 + (l & 15)) * 32;
  const int boffbase = (wn * 64 + (l & 15)) * 32;
  const int kc = (((l >> 4) ^ ((l >> 1) & 3)) << 3);   // swizzled chunk, elements

  STAGE(0, 0);
  int cur = 0;
  for (int t = 0; t < nt; ++t) {
    if (t + 1 < nt) STAGE(cur ^ 1, (t + 1) * 32);
    __builtin_amdgcn_sched_barrier(0);
    if (t + 1 < nt) { asm volatile("s_waitcnt vmcnt(4)" ::: "memory"); }
    else            { asm volatile("s_waitcnt vmcnt(0)" ::: "memory"); }
    __builtin_amdgcn_s_barrier();
    __builtin_amdgcn_sched_barrier(0);
    const u16* lab = laBase + cur * (256 * 32);
    const u16* lbb = lbBase + cur * (256 * 32);
    bf16x8 bfr[4];
#pragma unroll
    for (int ni = 0; ni < 4; ++ni)
      bfr[ni] = *(const bf16x8*)&lbb[boffbase + ni * 512 + kc];
#pragma unroll
    for (int mh = 0; mh < 2; ++mh) {
      bf16x8 afr[4];
#pragma unroll
      for (int mi = 0; mi < 4; ++mi)
        afr[mi] = *(const bf16x8*)&lab[aoffbase + (mh * 4 + mi) * 512 + kc];
      __builtin_amdgcn_s_setprio(1);
#pragma unroll
      for (int mi = 0; mi < 4; ++mi)
#pragma unroll
        for (int ni = 0; ni < 4; ++ni)
          acc[mh * 4 + mi][ni] =
              __builtin_amdgcn_mfma_f32_16x16x32_bf16(afr[mi], bfr[ni], acc[mh * 4 + mi][ni], 0, 0, 0);
      __builtin_amdgcn_s_setprio(0);
    }
    __builtin_amdgcn_sched_barrier(0);
    __builtin_amdgcn_s_barrier();
    cur ^= 1;
  }

  const int row0 = tm * 256 + wm * 128 + ((l >> 4) << 2);
  const int col0 = tn * 256 + wn * 64 + (l & 15);
#pragma unroll
  for (int mi = 0; mi < 8; ++mi) {
#pragma unroll
    for (int j = 0; j < 4; ++j) {
      int grow = row0 + mi * 16 + j;
      if (grow < Mvalid) {
#pragma unroll
        for (int ni = 0; ni < 4; ++ni) {
          int gcol = col0 + ni * 16;
          if (gcol < Nvalid) {
            float vv = acc[mi][ni][j];
            if (bias) vv += bias[gcol];
            Cb[(size_t)grow * ldc + gcol] = vv;
          }
        }
      }
    }
  }
}

static inline int imin(int a, int b) { return a < b ? a : b; }

extern "C" void kernel_launch(void* const* d_in, const int* in_sizes, int n_in,
                              void* d_out, int out_size, void* d_ws, size_t ws_size,
                              hipStream_t stream) {
  const float* signal = (const float*)d_in[0];
  const int*   bc_idx = (const int*)d_in[1];
  const float* bc_w   = (const float*)d_in[2];
  const float* tmpl[3] = { (const float*)d_in[3], (const float*)d_in[5], (const float*)d_in[7] };
  const float* tb[3]   = { (const float*)d_in[4], (const float*)d_in[6], (const float*)d_in[8] };
  const float* Wd = (const float*)d_in[9];
  const float* bd = (const float*)d_in[10];
  float* outp = (float*)d_out;

  char* ws = (char*)d_ws;
  size_t off = 0;
  auto alloc = [&](size_t b) -> void* {
    size_t o = (off + 255) & ~(size_t)255; off = o + b; return (void*)(ws + o);
  };
  u16* sigbf = (u16*)alloc((size_t)V_N * 544 * 2);
  u16* outL0 = (u16*)alloc((size_t)V_PAD * 96 * 2);
  u16* outL1 = (u16*)alloc((size_t)V_PAD * 128 * 2);
  u16* outL2 = (u16*)alloc((size_t)V_PAD * 256 * 2);      // split hi|lo
  u16* trot  = (u16*)alloc((size_t)1024 * 21760 * 2);     // max over layers; reused for WdT
  float* gemmC = (float*)alloc((size_t)6 * V_PAD * 768 * 4); // split-K partials (127 MB max)
  size_t o2 = (off + 255) & ~(size_t)255;
  u16* interp = (u16*)(ws + o2);
  size_t interpElems = (ws_size > o2) ? (ws_size - o2) / 2 : 0;

  { int total4 = V_N * 544 / 4;
    cvt_kernel<<<dim3((total4 + 255) / 256), dim3(256), 0, stream>>>(signal, sigbf, total4); }

  const int TnA[3] = {96, 128, 128}, CcA[3] = {544, 96, 128};
  const int SplitA[3] = {6, 4, 4};
  u16* outs[3] = { outL0, outL1, outL2 };
  const u16* cursig = sigbf;
  for (int L = 0; L < 3; ++L) {
    const int Tn = TnA[L], Cc = CcA[L];
    const int K = 40 * Cc, N = 8 * Tn, C8 = Cc / 8, C4 = Cc / 4;
    const int nsplit = SplitA[L];
    const int kchunk = ((K / 32 + nsplit - 1) / nsplit) * 32;  // multiple of 32
    const size_t cstride = (size_t)V_PAD * N;
    { int total = N * 40 * C4;
      trot_kernel<<<dim3((total + 255) / 256), dim3(256), 0, stream>>>(tmpl[L], trot, Tn, Cc, C4, total); }
    long crl = (long)(interpElems / (size_t)K) & ~(long)255;
    int cr;
    if (crl >= (long)V_PAD) cr = V_PAD;                 // single dispatch (preferred)
    else { cr = (crl > 3584) ? 3584 : (int)crl; if (cr < 256) cr = 256; }
    const int ntn = N / 256;
    for (int v0 = 0; v0 < V_PAD; v0 += cr) {
      int rows = imin(cr, V_PAD - v0);
      int nv = imin(rows, V_N - v0);
      { int total = nv * 40 * C8;
        interp_kernel<<<dim3((total + 255) / 256), dim3(256), 0, stream>>>(
            cursig, Cc, C8, bc_idx, bc_w, interp, v0, K, total); }
      int ntm = rows / 256;
      gemm256<<<dim3(ntm * ntn * nsplit), dim3(512), 0, stream>>>(
          interp, K, trot, K, gemmC + (size_t)v0 * N, N, cstride, nullptr, nv, N, kchunk, K, ntm, ntn);
    }
    { int total = V_N * Tn;
      int ldo = (L == 2) ? 256 : ((L == 0) ? 96 : 128);
      amp_kernel<<<dim3((total + 255) / 256), dim3(256), 0, stream>>>(
          gemmC, cstride, nsplit, tb[L], outs[L], Tn, ldo, (L == 2) ? 1 : 0, total); }
    cursig = outs[L];
  }

  { int total = V_PAD * 128;
    wdt_kernel<<<dim3((total + 255) / 256), dim3(256), 0, stream>>>(Wd, trot, total); }
  gemm256<<<dim3(27 * 27), dim3(512), 0, stream>>>(
      outL2, 256, trot, 256, outp, V_N, 0, bd, V_N, V_N, 256, 256, 27, 27);
}

// Round 5
// 909.576 us; speedup vs baseline: 4.2018x; 4.2018x over previous
//
#include <hip/hip_runtime.h>

typedef unsigned short u16;
typedef unsigned int   u32;
typedef __bf16 bf16x8 __attribute__((ext_vector_type(8)));
typedef float  f32x4  __attribute__((ext_vector_type(4)));
typedef u32    u32x4  __attribute__((ext_vector_type(4)));
typedef u16    u16x4  __attribute__((ext_vector_type(4)));

#define V_N   6890
#define V_PAD 6912

__device__ __forceinline__ float bf2f(u32 h) {
  union { u32 u; float f; } c; c.u = h << 16; return c.f;
}
__device__ __forceinline__ u16 f2bf(float f) {
  union { float f; u32 u; } c; c.f = f;
  return (u16)((c.u + 0x7fffu + ((c.u >> 16) & 1u)) >> 16);
}
__device__ __forceinline__ void gload_lds16(const void* g, void* l) {
  __builtin_amdgcn_global_load_lds((const __attribute__((address_space(1))) void*)g,
                                   (__attribute__((address_space(3))) void*)l, 16, 0, 0);
}

// ---- f32 -> bf16 (vec4) ----
__global__ void cvt_kernel(const float* __restrict__ in, u16* __restrict__ out, int total4) {
  int g = blockIdx.x * 256 + threadIdx.x;
  if (g >= total4) return;
  f32x4 v = *(const f32x4*)(in + (size_t)g * 4);
  u16x4 o; o.x = f2bf(v.x); o.y = f2bf(v.y); o.z = f2bf(v.z); o.w = f2bf(v.w);
  *(u16x4*)(out + (size_t)g * 4) = o;
}

// ---- build rotated templates, bf16, B^T layout ----
__global__ void trot_kernel(const float* __restrict__ T, u16* __restrict__ out,
                            int Tn, int Cc, int C4, int total) {
  int g = blockIdx.x * 256 + threadIdx.x;
  if (g >= total) return;
  int c4 = g % C4; int q = g / C4;
  int a = q & 7; q >>= 3;
  int r = q % 5; q /= 5;
  int t = q % Tn; int o = q / Tn;
  f32x4 s = *(const f32x4*)(T + (size_t)((t * 5 + r) * 8 + ((a - o + 8) & 7)) * Cc + c4 * 4);
  u16x4 d; d.x = f2bf(s.x); d.y = f2bf(s.y); d.z = f2bf(s.z); d.w = f2bf(s.w);
  *(u16x4*)(out + ((size_t)(o * Tn + t) * 40 + (r * 8 + a)) * Cc + c4 * 4) = d;
}

// ---- barycentric gather+interp ----
__global__ void interp_kernel(const u16* __restrict__ sig, int Cc, int C8,
                              const int* __restrict__ idx, const float* __restrict__ w,
                              u16* __restrict__ out, int v0, int Kl, int total) {
  int g = blockIdx.x * 256 + threadIdx.x;
  if (g >= total) return;
  int q = g / C8, c8 = g - q * C8;
  int vr = q / 40, ra = q - vr * 40;
  size_t ib = ((size_t)(v0 + vr) * 40 + ra) * 3;
  int i0 = idx[ib], i1 = idx[ib + 1], i2 = idx[ib + 2];
  float w0 = w[ib], w1 = w[ib + 1], w2 = w[ib + 2];
  u32x4 s0 = *(const u32x4*)(sig + (size_t)i0 * Cc + c8 * 8);
  u32x4 s1 = *(const u32x4*)(sig + (size_t)i1 * Cc + c8 * 8);
  u32x4 s2 = *(const u32x4*)(sig + (size_t)i2 * Cc + c8 * 8);
  u32x4 o;
#pragma unroll
  for (int j = 0; j < 4; ++j) {
    float lo = w0 * bf2f(s0[j] & 0xffffu) + w1 * bf2f(s1[j] & 0xffffu) + w2 * bf2f(s2[j] & 0xffffu);
    float hi = w0 * bf2f(s0[j] >> 16)     + w1 * bf2f(s1[j] >> 16)     + w2 * bf2f(s2[j] >> 16);
    o[j] = (u32)f2bf(lo) | ((u32)f2bf(hi) << 16);
  }
  *(u32x4*)(out + (size_t)vr * Kl + ra * Cc + c8 * 8) = o;
}

// ---- split-K reduce + relu(+bias) + angular max; optional split-bf16 (hi|lo) output ----
__global__ void amp_kernel(const float* __restrict__ Cin, size_t cstride, int nsplit,
                           const float* __restrict__ bias, u16* __restrict__ out,
                           int Tn, int ldo, int split, int total) {
  int g = blockIdx.x * 256 + threadIdx.x;
  if (g >= total) return;
  int t = g % Tn, v = g / Tn;
  const float* row = Cin + (size_t)v * (8 * Tn) + t;
  float acc[8];
#pragma unroll
  for (int o = 0; o < 8; ++o) acc[o] = row[(size_t)o * Tn];
  for (int s = 1; s < nsplit; ++s) {
    row += cstride;
#pragma unroll
    for (int o = 0; o < 8; ++o) acc[o] += row[(size_t)o * Tn];
  }
  float b = bias[t];
  float m = acc[0] + b;
#pragma unroll
  for (int o = 1; o < 8; ++o) m = fmaxf(m, acc[o] + b);
  m = fmaxf(m, 0.f);
  u16 hi = f2bf(m);
  out[(size_t)v * ldo + t] = hi;
  if (split) out[(size_t)v * ldo + Tn + t] = f2bf(m - bf2f(hi));
}

// ---- Wd [128][V] f32 -> WdT split-bf16 [V_PAD][256] (hi | lo along k) ----
__global__ void wdt_kernel(const float* __restrict__ Wd, u16* __restrict__ out, int total) {
  int g = blockIdx.x * 256 + threadIdx.x;
  if (g >= total) return;
  int k = g & 127, n = g >> 7;
  float v = (n < V_N) ? Wd[(size_t)k * V_N + n] : 0.f;
  u16 hi = f2bf(v);
  out[(size_t)n * 256 + k] = hi;
  out[(size_t)n * 256 + 128 + k] = f2bf(v - bf2f(hi));
}

// ---- 256x256 bf16 GEMM, BK=32, 8 waves (2Mx4N), 4-buffer LDS (128 KiB), 3-deep
//      counted-vmcnt prefetch (steady vmcnt(12), tail 8/4/0), bank-free swizzle
//      (phys_chunk = logical ^ ((row>>1)&3); 2-way aliasing = free), T5 setprio,
//      split-K partials, bijective XCD block mapping. C = A * B^T (+bias).
//      NOTE: __launch_bounds__(512,2) — acc needs 128 AGPRs; (512,4) caps the
//      unified file at 128/wave and spills everything to scratch (R4 disaster). ----
__global__ __launch_bounds__(512, 2) void gemm256(
    const u16* __restrict__ A, int lda,
    const u16* __restrict__ B, int ldb,
    float* __restrict__ C, int ldc, size_t cstride,
    const float* __restrict__ bias,
    int Mvalid, int Nvalid, int kchunk, int Ktot,
    int ntm, int ntn) {
  __shared__ __align__(16) u16 lA[4][256 * 32];
  __shared__ __align__(16) u16 lB[4][256 * 32];
  const int tid = threadIdx.x;
  const int w = tid >> 6, l = tid & 63;

  // bijective XCD chunking (m204)
  const int nb = gridDim.x, bid = blockIdx.x;
  const int q = nb >> 3, r = nb & 7;
  const int xcd = bid & 7, ii = bid >> 3;
  const int vb = (xcd < r ? xcd * (q + 1) : r * (q + 1) + (xcd - r) * q) + ii;
  const int per = ntm * ntn;
  const int s = vb / per;
  const int rem = vb - s * per;
  const int tm = rem / ntn, tn = rem - tm * ntn;
  const int kb = s * kchunk;
  int ke = kb + kchunk; if (ke > Ktot) ke = Ktot;
  const int nt = (ke - kb + 31) >> 5;
  float* Cb = C + (size_t)s * cstride;

  const u16* Ab = A + (size_t)(tm * 256) * lda + kb;
  const u16* Bb = B + (size_t)(tn * 256) * ldb + kb;

  // staging: linear LDS dest (wave-uniform base + lane*16B), pre-swizzled global col
  const int srow = tid >> 2;                                  // 0..127 (+i*128)
  const int scol = (((tid & 3) ^ ((tid >> 3) & 3)) << 3);     // elements
  u16* laBase = &lA[0][0];
  u16* lbBase = &lB[0][0];

  auto STAGE = [&](int buf, int k0) {
    const u16* ga = Ab + (size_t)srow * lda + k0 + scol;
    const u16* gb = Bb + (size_t)srow * ldb + k0 + scol;
    u16* la = laBase + buf * (256 * 32) + w * 512;   // +lane*8 u16 done by HW
    u16* lb = lbBase + buf * (256 * 32) + w * 512;
#pragma unroll
    for (int i = 0; i < 2; ++i) {
      gload_lds16(ga + (size_t)(i * 128) * lda, la + i * 4096);
      gload_lds16(gb + (size_t)(i * 128) * ldb, lb + i * 4096);
    }
  };

  f32x4 acc[8][4];
#pragma unroll
  for (int i = 0; i < 8; ++i)
#pragma unroll
    for (int j = 0; j < 4; ++j) acc[i][j] = (f32x4){0.f, 0.f, 0.f, 0.f};

  const int wm = w >> 2, wn = w & 3;
  const int aoffbase = (wm * 128 + (l & 15)) * 32;
  const int boffbase = (wn * 64 + (l & 15)) * 32;
  const int kc = (((l >> 4) ^ ((l >> 1) & 3)) << 3);   // swizzled chunk, elements

#pragma unroll
  for (int i = 0; i < 3; ++i) if (i < nt) STAGE(i, i * 32);

  for (int t = 0; t < nt; ++t) {
    if (t + 3 < nt) STAGE((t + 3) & 3, (t + 3) * 32);
    __builtin_amdgcn_sched_barrier(0);
    if (t + 3 < nt)      { asm volatile("s_waitcnt vmcnt(12)" ::: "memory"); }
    else if (t + 2 < nt) { asm volatile("s_waitcnt vmcnt(8)"  ::: "memory"); }
    else if (t + 1 < nt) { asm volatile("s_waitcnt vmcnt(4)"  ::: "memory"); }
    else                 { asm volatile("s_waitcnt vmcnt(0)"  ::: "memory"); }
    __builtin_amdgcn_s_barrier();
    __builtin_amdgcn_sched_barrier(0);
    const u16* lab = laBase + (t & 3) * (256 * 32);
    const u16* lbb = lbBase + (t & 3) * (256 * 32);
    bf16x8 bfr[4];
#pragma unroll
    for (int ni = 0; ni < 4; ++ni)
      bfr[ni] = *(const bf16x8*)&lbb[boffbase + ni * 512 + kc];
#pragma unroll
    for (int mh = 0; mh < 2; ++mh) {
      bf16x8 afr[4];
#pragma unroll
      for (int mi = 0; mi < 4; ++mi)
        afr[mi] = *(const bf16x8*)&lab[aoffbase + (mh * 4 + mi) * 512 + kc];
      __builtin_amdgcn_s_setprio(1);
#pragma unroll
      for (int mi = 0; mi < 4; ++mi)
#pragma unroll
        for (int ni = 0; ni < 4; ++ni)
          acc[mh * 4 + mi][ni] =
              __builtin_amdgcn_mfma_f32_16x16x32_bf16(afr[mi], bfr[ni], acc[mh * 4 + mi][ni], 0, 0, 0);
      __builtin_amdgcn_s_setprio(0);
    }
    __builtin_amdgcn_sched_barrier(0);
    __builtin_amdgcn_s_barrier();
  }

  const int row0 = tm * 256 + wm * 128 + ((l >> 4) << 2);
  const int col0 = tn * 256 + wn * 64 + (l & 15);
#pragma unroll
  for (int mi = 0; mi < 8; ++mi) {
#pragma unroll
    for (int j = 0; j < 4; ++j) {
      int grow = row0 + mi * 16 + j;
      if (grow < Mvalid) {
#pragma unroll
        for (int ni = 0; ni < 4; ++ni) {
          int gcol = col0 + ni * 16;
          if (gcol < Nvalid) {
            float vv = acc[mi][ni][j];
            if (bias) vv += bias[gcol];
            Cb[(size_t)grow * ldc + gcol] = vv;
          }
        }
      }
    }
  }
}

static inline int imin(int a, int b) { return a < b ? a : b; }

extern "C" void kernel_launch(void* const* d_in, const int* in_sizes, int n_in,
                              void* d_out, int out_size, void* d_ws, size_t ws_size,
                              hipStream_t stream) {
  const float* signal = (const float*)d_in[0];
  const int*   bc_idx = (const int*)d_in[1];
  const float* bc_w   = (const float*)d_in[2];
  const float* tmpl[3] = { (const float*)d_in[3], (const float*)d_in[5], (const float*)d_in[7] };
  const float* tb[3]   = { (const float*)d_in[4], (const float*)d_in[6], (const float*)d_in[8] };
  const float* Wd = (const float*)d_in[9];
  const float* bd = (const float*)d_in[10];
  float* outp = (float*)d_out;

  char* ws = (char*)d_ws;
  size_t off = 0;
  auto alloc = [&](size_t b) -> void* {
    size_t o = (off + 255) & ~(size_t)255; off = o + b; return (void*)(ws + o);
  };
  u16* sigbf = (u16*)alloc((size_t)V_N * 544 * 2);
  u16* outL0 = (u16*)alloc((size_t)V_PAD * 96 * 2);
  u16* outL1 = (u16*)alloc((size_t)V_PAD * 128 * 2);
  u16* outL2 = (u16*)alloc((size_t)V_PAD * 256 * 2);      // split hi|lo
  u16* trot  = (u16*)alloc((size_t)1024 * 21760 * 2);     // max over layers; reused for WdT
  float* gemmC = (float*)alloc((size_t)6 * V_PAD * 768 * 4); // split-K partials (127 MB max)
  size_t o2 = (off + 255) & ~(size_t)255;
  u16* interp = (u16*)(ws + o2);
  size_t interpElems = (ws_size > o2) ? (ws_size - o2) / 2 : 0;

  { int total4 = V_N * 544 / 4;
    cvt_kernel<<<dim3((total4 + 255) / 256), dim3(256), 0, stream>>>(signal, sigbf, total4); }

  const int TnA[3] = {96, 128, 128}, CcA[3] = {544, 96, 128};
  const int SplitA[3] = {6, 4, 4};
  u16* outs[3] = { outL0, outL1, outL2 };
  const u16* cursig = sigbf;
  for (int L = 0; L < 3; ++L) {
    const int Tn = TnA[L], Cc = CcA[L];
    const int K = 40 * Cc, N = 8 * Tn, C8 = Cc / 8, C4 = Cc / 4;
    const int nsplit = SplitA[L];
    const int kchunk = ((K / 32 + nsplit - 1) / nsplit) * 32;  // multiple of 32
    const size_t cstride = (size_t)V_PAD * N;
    { int total = N * 40 * C4;
      trot_kernel<<<dim3((total + 255) / 256), dim3(256), 0, stream>>>(tmpl[L], trot, Tn, Cc, C4, total); }
    long crl = (long)(interpElems / (size_t)K) & ~(long)255;
    int cr;
    if (crl >= (long)V_PAD) cr = V_PAD;                 // single dispatch (preferred)
    else { cr = (crl > 3584) ? 3584 : (int)crl; if (cr < 256) cr = 256; }
    const int ntn = N / 256;
    for (int v0 = 0; v0 < V_PAD; v0 += cr) {
      int rows = imin(cr, V_PAD - v0);
      int nv = imin(rows, V_N - v0);
      { int total = nv * 40 * C8;
        interp_kernel<<<dim3((total + 255) / 256), dim3(256), 0, stream>>>(
            cursig, Cc, C8, bc_idx, bc_w, interp, v0, K, total); }
      int ntm = rows / 256;
      gemm256<<<dim3(ntm * ntn * nsplit), dim3(512), 0, stream>>>(
          interp, K, trot, K, gemmC + (size_t)v0 * N, N, cstride, nullptr, nv, N, kchunk, K, ntm, ntn);
    }
    { int total = V_N * Tn;
      int ldo = (L == 2) ? 256 : ((L == 0) ? 96 : 128);
      amp_kernel<<<dim3((total + 255) / 256), dim3(256), 0, stream>>>(
          gemmC, cstride, nsplit, tb[L], outs[L], Tn, ldo, (L == 2) ? 1 : 0, total); }
    cursig = outs[L];
  }

  { int total = V_PAD * 128;
    wdt_kernel<<<dim3((total + 255) / 256), dim3(256), 0, stream>>>(Wd, trot, total); }
  gemm256<<<dim3(27 * 27), dim3(512), 0, stream>>>(
      outL2, 256, trot, 256, outp, V_N, 0, bd, V_N, V_N, 256, 256, 27, 27);
}

// Round 6
// 860.091 us; speedup vs baseline: 4.4435x; 1.0575x over previous
//
#include <hip/hip_runtime.h>

typedef unsigned short u16;
typedef unsigned int   u32;
typedef __bf16 bf16x8 __attribute__((ext_vector_type(8)));
typedef float  f32x4  __attribute__((ext_vector_type(4)));
typedef u32    u32x4  __attribute__((ext_vector_type(4)));
typedef u16    u16x4  __attribute__((ext_vector_type(4)));

#define V_N   6890
#define V_PAD 6912

__device__ __forceinline__ float bf2f(u32 h) {
  union { u32 u; float f; } c; c.u = h << 16; return c.f;
}
__device__ __forceinline__ u16 f2bf(float f) {
  union { float f; u32 u; } c; c.f = f;
  return (u16)((c.u + 0x7fffu + ((c.u >> 16) & 1u)) >> 16);
}
__device__ __forceinline__ void gload_lds16(const void* g, void* l) {
  __builtin_amdgcn_global_load_lds((const __attribute__((address_space(1))) void*)g,
                                   (__attribute__((address_space(3))) void*)l, 16, 0, 0);
}

// ---- f32 -> bf16 (vec4) ----
__global__ void cvt_kernel(const float* __restrict__ in, u16* __restrict__ out, int total4) {
  int g = blockIdx.x * 256 + threadIdx.x;
  if (g >= total4) return;
  f32x4 v = *(const f32x4*)(in + (size_t)g * 4);
  u16x4 o; o.x = f2bf(v.x); o.y = f2bf(v.y); o.z = f2bf(v.z); o.w = f2bf(v.w);
  *(u16x4*)(out + (size_t)g * 4) = o;
}

// ---- build rotated templates, bf16, B^T layout ----
__global__ void trot_kernel(const float* __restrict__ T, u16* __restrict__ out,
                            int Tn, int Cc, int C4, int total) {
  int g = blockIdx.x * 256 + threadIdx.x;
  if (g >= total) return;
  int c4 = g % C4; int q = g / C4;
  int a = q & 7; q >>= 3;
  int r = q % 5; q /= 5;
  int t = q % Tn; int o = q / Tn;
  f32x4 s = *(const f32x4*)(T + (size_t)((t * 5 + r) * 8 + ((a - o + 8) & 7)) * Cc + c4 * 4);
  u16x4 d; d.x = f2bf(s.x); d.y = f2bf(s.y); d.z = f2bf(s.z); d.w = f2bf(s.w);
  *(u16x4*)(out + ((size_t)(o * Tn + t) * 40 + (r * 8 + a)) * Cc + c4 * 4) = d;
}

// ---- barycentric gather+interp ----
__global__ void interp_kernel(const u16* __restrict__ sig, int Cc, int C8,
                              const int* __restrict__ idx, const float* __restrict__ w,
                              u16* __restrict__ out, int v0, int Kl, int total) {
  int g = blockIdx.x * 256 + threadIdx.x;
  if (g >= total) return;
  int q = g / C8, c8 = g - q * C8;
  int vr = q / 40, ra = q - vr * 40;
  size_t ib = ((size_t)(v0 + vr) * 40 + ra) * 3;
  int i0 = idx[ib], i1 = idx[ib + 1], i2 = idx[ib + 2];
  float w0 = w[ib], w1 = w[ib + 1], w2 = w[ib + 2];
  u32x4 s0 = *(const u32x4*)(sig + (size_t)i0 * Cc + c8 * 8);
  u32x4 s1 = *(const u32x4*)(sig + (size_t)i1 * Cc + c8 * 8);
  u32x4 s2 = *(const u32x4*)(sig + (size_t)i2 * Cc + c8 * 8);
  u32x4 o;
#pragma unroll
  for (int j = 0; j < 4; ++j) {
    float lo = w0 * bf2f(s0[j] & 0xffffu) + w1 * bf2f(s1[j] & 0xffffu) + w2 * bf2f(s2[j] & 0xffffu);
    float hi = w0 * bf2f(s0[j] >> 16)     + w1 * bf2f(s1[j] >> 16)     + w2 * bf2f(s2[j] >> 16);
    o[j] = (u32)f2bf(lo) | ((u32)f2bf(hi) << 16);
  }
  *(u32x4*)(out + (size_t)vr * Kl + ra * Cc + c8 * 8) = o;
}

// ---- split-K reduce + relu(+bias) + angular max; optional split-bf16 (hi|lo) output ----
__global__ void amp_kernel(const float* __restrict__ Cin, size_t cstride, int nsplit,
                           const float* __restrict__ bias, u16* __restrict__ out,
                           int Tn, int ldo, int split, int total) {
  int g = blockIdx.x * 256 + threadIdx.x;
  if (g >= total) return;
  int t = g % Tn, v = g / Tn;
  const float* row = Cin + (size_t)v * (8 * Tn) + t;
  float acc[8];
#pragma unroll
  for (int o = 0; o < 8; ++o) acc[o] = row[(size_t)o * Tn];
  for (int s = 1; s < nsplit; ++s) {
    row += cstride;
#pragma unroll
    for (int o = 0; o < 8; ++o) acc[o] += row[(size_t)o * Tn];
  }
  float b = bias[t];
  float m = acc[0] + b;
#pragma unroll
  for (int o = 1; o < 8; ++o) m = fmaxf(m, acc[o] + b);
  m = fmaxf(m, 0.f);
  u16 hi = f2bf(m);
  out[(size_t)v * ldo + t] = hi;
  if (split) out[(size_t)v * ldo + Tn + t] = f2bf(m - bf2f(hi));
}

// ---- Wd [128][V] f32 -> WdT split-bf16 [V_PAD][256] (hi | lo along k) ----
__global__ void wdt_kernel(const float* __restrict__ Wd, u16* __restrict__ out, int total) {
  int g = blockIdx.x * 256 + threadIdx.x;
  if (g >= total) return;
  int k = g & 127, n = g >> 7;
  float v = (n < V_N) ? Wd[(size_t)k * V_N + n] : 0.f;
  u16 hi = f2bf(v);
  out[(size_t)n * 256 + k] = hi;
  out[(size_t)n * 256 + 128 + k] = f2bf(v - bf2f(hi));
}

// ---- 256x256 bf16 GEMM, BK=64, 8 waves (2Mx4N), double-buffered LDS (128 KiB),
//      counted vmcnt(8) prefetch (T4), 4-phase quadrant interleave (T3) with
//      setprio MFMA clusters (T5), verified XOR swizzle (conflicts=0), split-K
//      partials, bijective XCD block mapping. C = A * B^T (+bias).
//      __launch_bounds__(512,2): acc needs 128 regs; (512,4) spills (R4 lesson). ----
__global__ __launch_bounds__(512, 2) void gemm256(
    const u16* __restrict__ A, int lda,
    const u16* __restrict__ B, int ldb,
    float* __restrict__ C, int ldc, size_t cstride,
    const float* __restrict__ bias,
    int Mvalid, int Nvalid, int kchunk, int Ktot,
    int ntm, int ntn) {
  __shared__ __align__(16) u16 lA[2][256 * 64];
  __shared__ __align__(16) u16 lB[2][256 * 64];
  const int tid = threadIdx.x;
  const int w = tid >> 6, l = tid & 63;

  // bijective XCD chunking (m204)
  const int nb = gridDim.x, bid = blockIdx.x;
  const int q = nb >> 3, r = nb & 7;
  const int xcd = bid & 7, ii = bid >> 3;
  const int vb = (xcd < r ? xcd * (q + 1) : r * (q + 1) + (xcd - r) * q) + ii;
  const int per = ntm * ntn;
  const int s = vb / per;
  const int rem = vb - s * per;
  const int tm = rem / ntn, tn = rem - tm * ntn;
  const int kb = s * kchunk;
  int ke = kb + kchunk; if (ke > Ktot) ke = Ktot;
  const int nt = (ke - kb + 63) >> 6;
  float* Cb = C + (size_t)s * cstride;

  const u16* Ab = A + (size_t)(tm * 256) * lda + kb;
  const u16* Bb = B + (size_t)(tn * 256) * ldb + kb;

  // staging: linear LDS dest (wave-uniform base + lane*16B), pre-swizzled global col
  const int srow = tid >> 3;                                  // 0..63 (+i*64)
  const int scol = (((l & 7) ^ (srow & 7)) << 3);             // elements
  u16* laBase = &lA[0][0];
  u16* lbBase = &lB[0][0];

  auto STAGE = [&](int buf, int k0) {
    const u16* ga = Ab + (size_t)srow * lda + k0 + scol;
    const u16* gb = Bb + (size_t)srow * ldb + k0 + scol;
    u16* la = laBase + buf * (256 * 64) + w * 512;
    u16* lb = lbBase + buf * (256 * 64) + w * 512;
#pragma unroll
    for (int i = 0; i < 4; ++i) {
      gload_lds16(ga + (size_t)(i * 64) * lda, la + i * 4096);
      gload_lds16(gb + (size_t)(i * 64) * ldb, lb + i * 4096);
    }
  };

  f32x4 acc[8][4];
#pragma unroll
  for (int i = 0; i < 8; ++i)
#pragma unroll
    for (int j = 0; j < 4; ++j) acc[i][j] = (f32x4){0.f, 0.f, 0.f, 0.f};

  const int wm = w >> 2, wn = w & 3;
  const int aoffbase = (wm * 128 + (l & 15)) * 64;
  const int boffbase = (wn * 64 + (l & 15)) * 64;
  const int ksel = l >> 4, swz = l & 7;
  const int kc0 = ((ksel ^ swz) << 3);          // kk=0 chunk (swizzled)
  const int kc1 = (((4 + ksel) ^ swz) << 3);    // kk=1 chunk (swizzled)

  STAGE(0, 0);
  for (int t = 0; t < nt; ++t) {
    const int buf = t & 1;
    if (t + 1 < nt) STAGE(buf ^ 1, (t + 1) * 64);
    __builtin_amdgcn_sched_barrier(0);
    if (t + 1 < nt) { asm volatile("s_waitcnt vmcnt(8)" ::: "memory"); }
    else            { asm volatile("s_waitcnt vmcnt(0)" ::: "memory"); }
    __builtin_amdgcn_s_barrier();
    __builtin_amdgcn_sched_barrier(0);
    const u16* lab = laBase + buf * (256 * 64);
    const u16* lbb = lbBase + buf * (256 * 64);

    bf16x8 af0[4], af1[4], bf0[4], bf1[4];
    // ---- phase Q0: (m0-3) x (n0-1), 12 ds_reads, 16 MFMA ----
#pragma unroll
    for (int mi = 0; mi < 4; ++mi) {
      af0[mi] = *(const bf16x8*)&lab[aoffbase + mi * 1024 + kc0];
      af1[mi] = *(const bf16x8*)&lab[aoffbase + mi * 1024 + kc1];
    }
#pragma unroll
    for (int ni = 0; ni < 2; ++ni) {
      bf0[ni] = *(const bf16x8*)&lbb[boffbase + ni * 1024 + kc0];
      bf1[ni] = *(const bf16x8*)&lbb[boffbase + ni * 1024 + kc1];
    }
    asm volatile("s_waitcnt lgkmcnt(0)" ::: "memory");
    __builtin_amdgcn_sched_barrier(0);
    __builtin_amdgcn_s_setprio(1);
#pragma unroll
    for (int mi = 0; mi < 4; ++mi)
#pragma unroll
      for (int ni = 0; ni < 2; ++ni) {
        acc[mi][ni] = __builtin_amdgcn_mfma_f32_16x16x32_bf16(af0[mi], bf0[ni], acc[mi][ni], 0, 0, 0);
        acc[mi][ni] = __builtin_amdgcn_mfma_f32_16x16x32_bf16(af1[mi], bf1[ni], acc[mi][ni], 0, 0, 0);
      }
    __builtin_amdgcn_s_setprio(0);
    __builtin_amdgcn_s_barrier();
    // ---- phase Q1: (m0-3) x (n2-3), 4 ds_reads, 16 MFMA ----
#pragma unroll
    for (int ni = 2; ni < 4; ++ni) {
      bf0[ni] = *(const bf16x8*)&lbb[boffbase + ni * 1024 + kc0];
      bf1[ni] = *(const bf16x8*)&lbb[boffbase + ni * 1024 + kc1];
    }
    asm volatile("s_waitcnt lgkmcnt(0)" ::: "memory");
    __builtin_amdgcn_sched_barrier(0);
    __builtin_amdgcn_s_setprio(1);
#pragma unroll
    for (int mi = 0; mi < 4; ++mi)
#pragma unroll
      for (int ni = 2; ni < 4; ++ni) {
        acc[mi][ni] = __builtin_amdgcn_mfma_f32_16x16x32_bf16(af0[mi], bf0[ni], acc[mi][ni], 0, 0, 0);
        acc[mi][ni] = __builtin_amdgcn_mfma_f32_16x16x32_bf16(af1[mi], bf1[ni], acc[mi][ni], 0, 0, 0);
      }
    __builtin_amdgcn_s_setprio(0);
    __builtin_amdgcn_s_barrier();
    // ---- phase Q2: (m4-7) x (n0-1), 8 ds_reads (reuse af regs), 16 MFMA ----
#pragma unroll
    for (int mi = 0; mi < 4; ++mi) {
      af0[mi] = *(const bf16x8*)&lab[aoffbase + (4 + mi) * 1024 + kc0];
      af1[mi] = *(const bf16x8*)&lab[aoffbase + (4 + mi) * 1024 + kc1];
    }
    asm volatile("s_waitcnt lgkmcnt(0)" ::: "memory");
    __builtin_amdgcn_sched_barrier(0);
    __builtin_amdgcn_s_setprio(1);
#pragma unroll
    for (int mi = 0; mi < 4; ++mi)
#pragma unroll
      for (int ni = 0; ni < 2; ++ni) {
        acc[4 + mi][ni] = __builtin_amdgcn_mfma_f32_16x16x32_bf16(af0[mi], bf0[ni], acc[4 + mi][ni], 0, 0, 0);
        acc[4 + mi][ni] = __builtin_amdgcn_mfma_f32_16x16x32_bf16(af1[mi], bf1[ni], acc[4 + mi][ni], 0, 0, 0);
      }
    __builtin_amdgcn_s_setprio(0);
    __builtin_amdgcn_s_barrier();   // protects buf: all reads done before next STAGE overwrites
    // ---- phase Q3: (m4-7) x (n2-3), 0 ds_reads, 16 MFMA ----
    __builtin_amdgcn_s_setprio(1);
#pragma unroll
    for (int mi = 0; mi < 4; ++mi)
#pragma unroll
      for (int ni = 2; ni < 4; ++ni) {
        acc[4 + mi][ni] = __builtin_amdgcn_mfma_f32_16x16x32_bf16(af0[mi], bf0[ni], acc[4 + mi][ni], 0, 0, 0);
        acc[4 + mi][ni] = __builtin_amdgcn_mfma_f32_16x16x32_bf16(af1[mi], bf1[ni], acc[4 + mi][ni], 0, 0, 0);
      }
    __builtin_amdgcn_s_setprio(0);
  }

  const int row0 = tm * 256 + wm * 128 + ((l >> 4) << 2);
  const int col0 = tn * 256 + wn * 64 + (l & 15);
#pragma unroll
  for (int mi = 0; mi < 8; ++mi) {
#pragma unroll
    for (int j = 0; j < 4; ++j) {
      int grow = row0 + mi * 16 + j;
      if (grow < Mvalid) {
#pragma unroll
        for (int ni = 0; ni < 4; ++ni) {
          int gcol = col0 + ni * 16;
          if (gcol < Nvalid) {
            float vv = acc[mi][ni][j];
            if (bias) vv += bias[gcol];
            Cb[(size_t)grow * ldc + gcol] = vv;
          }
        }
      }
    }
  }
}

static inline int imin(int a, int b) { return a < b ? a : b; }

extern "C" void kernel_launch(void* const* d_in, const int* in_sizes, int n_in,
                              void* d_out, int out_size, void* d_ws, size_t ws_size,
                              hipStream_t stream) {
  const float* signal = (const float*)d_in[0];
  const int*   bc_idx = (const int*)d_in[1];
  const float* bc_w   = (const float*)d_in[2];
  const float* tmpl[3] = { (const float*)d_in[3], (const float*)d_in[5], (const float*)d_in[7] };
  const float* tb[3]   = { (const float*)d_in[4], (const float*)d_in[6], (const float*)d_in[8] };
  const float* Wd = (const float*)d_in[9];
  const float* bd = (const float*)d_in[10];
  float* outp = (float*)d_out;

  char* ws = (char*)d_ws;
  size_t off = 0;
  auto alloc = [&](size_t b) -> void* {
    size_t o = (off + 255) & ~(size_t)255; off = o + b; return (void*)(ws + o);
  };
  u16* sigbf = (u16*)alloc((size_t)V_N * 544 * 2);
  u16* outL0 = (u16*)alloc((size_t)V_PAD * 96 * 2);
  u16* outL1 = (u16*)alloc((size_t)V_PAD * 128 * 2);
  u16* outL2 = (u16*)alloc((size_t)V_PAD * 256 * 2);      // split hi|lo
  u16* trot  = (u16*)alloc((size_t)1024 * 21760 * 2);     // max over layers; reused for WdT
  float* gemmC = (float*)alloc((size_t)6 * V_PAD * 768 * 4); // split-K partials (127 MB max)
  size_t o2 = (off + 255) & ~(size_t)255;
  u16* interp = (u16*)(ws + o2);
  size_t interpElems = (ws_size > o2) ? (ws_size - o2) / 2 : 0;

  { int total4 = V_N * 544 / 4;
    cvt_kernel<<<dim3((total4 + 255) / 256), dim3(256), 0, stream>>>(signal, sigbf, total4); }

  const int TnA[3] = {96, 128, 128}, CcA[3] = {544, 96, 128};
  const int SplitA[3] = {6, 4, 4};
  u16* outs[3] = { outL0, outL1, outL2 };
  const u16* cursig = sigbf;
  for (int L = 0; L < 3; ++L) {
    const int Tn = TnA[L], Cc = CcA[L];
    const int K = 40 * Cc, N = 8 * Tn, C8 = Cc / 8, C4 = Cc / 4;
    const int nsplit = SplitA[L];
    const int kchunk = ((K / 64 + nsplit - 1) / nsplit) * 64;  // multiple of 64
    const size_t cstride = (size_t)V_PAD * N;
    { int total = N * 40 * C4;
      trot_kernel<<<dim3((total + 255) / 256), dim3(256), 0, stream>>>(tmpl[L], trot, Tn, Cc, C4, total); }
    long crl = (long)(interpElems / (size_t)K) & ~(long)255;
    int cr;
    if (crl >= (long)V_PAD) cr = V_PAD;                 // single dispatch (preferred)
    else { cr = (crl > 3584) ? 3584 : (int)crl; if (cr < 256) cr = 256; }
    const int ntn = N / 256;
    for (int v0 = 0; v0 < V_PAD; v0 += cr) {
      int rows = imin(cr, V_PAD - v0);
      int nv = imin(rows, V_N - v0);
      { int total = nv * 40 * C8;
        interp_kernel<<<dim3((total + 255) / 256), dim3(256), 0, stream>>>(
            cursig, Cc, C8, bc_idx, bc_w, interp, v0, K, total); }
      int ntm = rows / 256;
      gemm256<<<dim3(ntm * ntn * nsplit), dim3(512), 0, stream>>>(
          interp, K, trot, K, gemmC + (size_t)v0 * N, N, cstride, nullptr, nv, N, kchunk, K, ntm, ntn);
    }
    { int total = V_N * Tn;
      int ldo = (L == 2) ? 256 : ((L == 0) ? 96 : 128);
      amp_kernel<<<dim3((total + 255) / 256), dim3(256), 0, stream>>>(
          gemmC, cstride, nsplit, tb[L], outs[L], Tn, ldo, (L == 2) ? 1 : 0, total); }
    cursig = outs[L];
  }

  { int total = V_PAD * 128;
    wdt_kernel<<<dim3((total + 255) / 256), dim3(256), 0, stream>>>(Wd, trot, total); }
  gemm256<<<dim3(27 * 27), dim3(512), 0, stream>>>(
      outL2, 256, trot, 256, outp, V_N, 0, bd, V_N, V_N, 256, 256, 27, 27);
}

// Round 7
// 833.064 us; speedup vs baseline: 4.5877x; 1.0324x over previous
//
#include <hip/hip_runtime.h>

typedef unsigned short u16;
typedef unsigned int   u32;
typedef __bf16 bf16x8 __attribute__((ext_vector_type(8)));
typedef float  f32x4  __attribute__((ext_vector_type(4)));
typedef u32    u32x4  __attribute__((ext_vector_type(4)));
typedef u16    u16x4  __attribute__((ext_vector_type(4)));

#define V_N   6890
#define V_PAD 6912

__device__ __forceinline__ float bf2f(u32 h) {
  union { u32 u; float f; } c; c.u = h << 16; return c.f;
}
__device__ __forceinline__ u16 f2bf(float f) {
  union { float f; u32 u; } c; c.f = f;
  return (u16)((c.u + 0x7fffu + ((c.u >> 16) & 1u)) >> 16);
}
__device__ __forceinline__ void gload_lds16(const void* g, void* l) {
  __builtin_amdgcn_global_load_lds((const __attribute__((address_space(1))) void*)g,
                                   (__attribute__((address_space(3))) void*)l, 16, 0, 0);
}

// ---- f32 -> bf16 (vec4) ----
__global__ void cvt_kernel(const float* __restrict__ in, u16* __restrict__ out, int total4) {
  int g = blockIdx.x * 256 + threadIdx.x;
  if (g >= total4) return;
  f32x4 v = *(const f32x4*)(in + (size_t)g * 4);
  u16x4 o; o.x = f2bf(v.x); o.y = f2bf(v.y); o.z = f2bf(v.z); o.w = f2bf(v.w);
  *(u16x4*)(out + (size_t)g * 4) = o;
}

// ---- build rotated templates, bf16, B^T layout ----
__global__ void trot_kernel(const float* __restrict__ T, u16* __restrict__ out,
                            int Tn, int Cc, int C4, int total) {
  int g = blockIdx.x * 256 + threadIdx.x;
  if (g >= total) return;
  int c4 = g % C4; int q = g / C4;
  int a = q & 7; q >>= 3;
  int r = q % 5; q /= 5;
  int t = q % Tn; int o = q / Tn;
  f32x4 s = *(const f32x4*)(T + (size_t)((t * 5 + r) * 8 + ((a - o + 8) & 7)) * Cc + c4 * 4);
  u16x4 d; d.x = f2bf(s.x); d.y = f2bf(s.y); d.z = f2bf(s.z); d.w = f2bf(s.w);
  *(u16x4*)(out + ((size_t)(o * Tn + t) * 40 + (r * 8 + a)) * Cc + c4 * 4) = d;
}

// ---- barycentric gather+interp ----
__global__ void interp_kernel(const u16* __restrict__ sig, int Cc, int C8,
                              const int* __restrict__ idx, const float* __restrict__ w,
                              u16* __restrict__ out, int v0, int Kl, int total) {
  int g = blockIdx.x * 256 + threadIdx.x;
  if (g >= total) return;
  int q = g / C8, c8 = g - q * C8;
  int vr = q / 40, ra = q - vr * 40;
  size_t ib = ((size_t)(v0 + vr) * 40 + ra) * 3;
  int i0 = idx[ib], i1 = idx[ib + 1], i2 = idx[ib + 2];
  float w0 = w[ib], w1 = w[ib + 1], w2 = w[ib + 2];
  u32x4 s0 = *(const u32x4*)(sig + (size_t)i0 * Cc + c8 * 8);
  u32x4 s1 = *(const u32x4*)(sig + (size_t)i1 * Cc + c8 * 8);
  u32x4 s2 = *(const u32x4*)(sig + (size_t)i2 * Cc + c8 * 8);
  u32x4 o;
#pragma unroll
  for (int j = 0; j < 4; ++j) {
    float lo = w0 * bf2f(s0[j] & 0xffffu) + w1 * bf2f(s1[j] & 0xffffu) + w2 * bf2f(s2[j] & 0xffffu);
    float hi = w0 * bf2f(s0[j] >> 16)     + w1 * bf2f(s1[j] >> 16)     + w2 * bf2f(s2[j] >> 16);
    o[j] = (u32)f2bf(lo) | ((u32)f2bf(hi) << 16);
  }
  *(u32x4*)(out + (size_t)vr * Kl + ra * Cc + c8 * 8) = o;
}

// ---- split-K reduce + relu(+bias) + angular max; optional split-bf16 (hi|lo) output ----
__global__ void amp_kernel(const float* __restrict__ Cin, size_t cstride, int nsplit,
                           const float* __restrict__ bias, u16* __restrict__ out,
                           int Tn, int ldo, int split, int total) {
  int g = blockIdx.x * 256 + threadIdx.x;
  if (g >= total) return;
  int t = g % Tn, v = g / Tn;
  const float* row = Cin + (size_t)v * (8 * Tn) + t;
  float acc[8];
#pragma unroll
  for (int o = 0; o < 8; ++o) acc[o] = row[(size_t)o * Tn];
  for (int s = 1; s < nsplit; ++s) {
    row += cstride;
#pragma unroll
    for (int o = 0; o < 8; ++o) acc[o] += row[(size_t)o * Tn];
  }
  float b = bias[t];
  float m = acc[0] + b;
#pragma unroll
  for (int o = 1; o < 8; ++o) m = fmaxf(m, acc[o] + b);
  m = fmaxf(m, 0.f);
  u16 hi = f2bf(m);
  out[(size_t)v * ldo + t] = hi;
  if (split) out[(size_t)v * ldo + Tn + t] = f2bf(m - bf2f(hi));
}

// ---- Wd [128][V] f32 -> WdT split-bf16 [V_PAD][256] (hi | lo along k) ----
__global__ void wdt_kernel(const float* __restrict__ Wd, u16* __restrict__ out, int total) {
  int g = blockIdx.x * 256 + threadIdx.x;
  if (g >= total) return;
  int k = g & 127, n = g >> 7;
  float v = (n < V_N) ? Wd[(size_t)k * V_N + n] : 0.f;
  u16 hi = f2bf(v);
  out[(size_t)n * 256 + k] = hi;
  out[(size_t)n * 256 + 128 + k] = f2bf(v - bf2f(hi));
}

// ---- 256x256 bf16 GEMM, BK=64, 8 waves (2Mx4N), double-buffered LDS (128 KiB),
//      counted vmcnt(8) prefetch, COMPILER-SCHEDULED tile body (R3-proven: the
//      compiler's fine-grained lgkmcnt interleaves ds_reads among MFMAs; R6's
//      explicit per-phase lgkmcnt(0)+sched_barrier serialized it, -30%),
//      T5 setprio MFMA clusters, verified XOR swizzle (conflicts=0), split-K
//      partials, bijective XCD block mapping. C = A * B^T (+bias).
//      __launch_bounds__(512,2): acc needs 128 regs; (512,4) spills (R4 lesson). ----
__global__ __launch_bounds__(512, 2) void gemm256(
    const u16* __restrict__ A, int lda,
    const u16* __restrict__ B, int ldb,
    float* __restrict__ C, int ldc, size_t cstride,
    const float* __restrict__ bias,
    int Mvalid, int Nvalid, int kchunk, int Ktot,
    int ntm, int ntn) {
  __shared__ __align__(16) u16 lA[2][256 * 64];
  __shared__ __align__(16) u16 lB[2][256 * 64];
  const int tid = threadIdx.x;
  const int w = tid >> 6, l = tid & 63;

  // bijective XCD chunking (m204)
  const int nb = gridDim.x, bid = blockIdx.x;
  const int q = nb >> 3, r = nb & 7;
  const int xcd = bid & 7, ii = bid >> 3;
  const int vb = (xcd < r ? xcd * (q + 1) : r * (q + 1) + (xcd - r) * q) + ii;
  const int per = ntm * ntn;
  const int s = vb / per;
  const int rem = vb - s * per;
  const int tm = rem / ntn, tn = rem - tm * ntn;
  const int kb = s * kchunk;
  int ke = kb + kchunk; if (ke > Ktot) ke = Ktot;
  const int nt = (ke - kb + 63) >> 6;
  float* Cb = C + (size_t)s * cstride;

  const u16* Ab = A + (size_t)(tm * 256) * lda + kb;
  const u16* Bb = B + (size_t)(tn * 256) * ldb + kb;

  // staging: linear LDS dest (wave-uniform base + lane*16B), pre-swizzled global col
  const int srow = tid >> 3;                                  // 0..63 (+i*64)
  const int scol = (((l & 7) ^ (srow & 7)) << 3);             // elements
  u16* laBase = &lA[0][0];
  u16* lbBase = &lB[0][0];

  auto STAGE = [&](int buf, int k0) {
    const u16* ga = Ab + (size_t)srow * lda + k0 + scol;
    const u16* gb = Bb + (size_t)srow * ldb + k0 + scol;
    u16* la = laBase + buf * (256 * 64) + w * 512;
    u16* lb = lbBase + buf * (256 * 64) + w * 512;
#pragma unroll
    for (int i = 0; i < 4; ++i) {
      gload_lds16(ga + (size_t)(i * 64) * lda, la + i * 4096);
      gload_lds16(gb + (size_t)(i * 64) * ldb, lb + i * 4096);
    }
  };

  f32x4 acc[8][4];
#pragma unroll
  for (int i = 0; i < 8; ++i)
#pragma unroll
    for (int j = 0; j < 4; ++j) acc[i][j] = (f32x4){0.f, 0.f, 0.f, 0.f};

  const int wm = w >> 2, wn = w & 3;
  const int aoffbase = (wm * 128 + (l & 15)) * 64;
  const int boffbase = (wn * 64 + (l & 15)) * 64;
  const int ksel = l >> 4, swz = l & 7;
  const int kc0 = ((ksel ^ swz) << 3);          // kk=0 chunk (swizzled)
  const int kc1 = (((4 + ksel) ^ swz) << 3);    // kk=1 chunk (swizzled)

  STAGE(0, 0);
  int cur = 0;
  for (int t = 0; t < nt; ++t) {
    if (t + 1 < nt) STAGE(cur ^ 1, (t + 1) * 64);
    __builtin_amdgcn_sched_barrier(0);
    if (t + 1 < nt) { asm volatile("s_waitcnt vmcnt(8)" ::: "memory"); }
    else            { asm volatile("s_waitcnt vmcnt(0)" ::: "memory"); }
    __builtin_amdgcn_s_barrier();
    __builtin_amdgcn_sched_barrier(0);
    const u16* lab = laBase + cur * (256 * 64);
    const u16* lbb = lbBase + cur * (256 * 64);
#pragma unroll
    for (int kk = 0; kk < 2; ++kk) {
      const int kc = kk ? kc1 : kc0;
      bf16x8 bfr[4];
#pragma unroll
      for (int ni = 0; ni < 4; ++ni)
        bfr[ni] = *(const bf16x8*)&lbb[boffbase + ni * 1024 + kc];
#pragma unroll
      for (int mh = 0; mh < 2; ++mh) {
        bf16x8 afr[4];
#pragma unroll
        for (int mi = 0; mi < 4; ++mi)
          afr[mi] = *(const bf16x8*)&lab[aoffbase + (mh * 4 + mi) * 1024 + kc];
        __builtin_amdgcn_s_setprio(1);
#pragma unroll
        for (int mi = 0; mi < 4; ++mi)
#pragma unroll
          for (int ni = 0; ni < 4; ++ni)
            acc[mh * 4 + mi][ni] =
                __builtin_amdgcn_mfma_f32_16x16x32_bf16(afr[mi], bfr[ni], acc[mh * 4 + mi][ni], 0, 0, 0);
        __builtin_amdgcn_s_setprio(0);
      }
    }
    __builtin_amdgcn_sched_barrier(0);
    __builtin_amdgcn_s_barrier();
    cur ^= 1;
  }

  const int row0 = tm * 256 + wm * 128 + ((l >> 4) << 2);
  const int col0 = tn * 256 + wn * 64 + (l & 15);
#pragma unroll
  for (int mi = 0; mi < 8; ++mi) {
#pragma unroll
    for (int j = 0; j < 4; ++j) {
      int grow = row0 + mi * 16 + j;
      if (grow < Mvalid) {
#pragma unroll
        for (int ni = 0; ni < 4; ++ni) {
          int gcol = col0 + ni * 16;
          if (gcol < Nvalid) {
            float vv = acc[mi][ni][j];
            if (bias) vv += bias[gcol];
            Cb[(size_t)grow * ldc + gcol] = vv;
          }
        }
      }
    }
  }
}

static inline int imin(int a, int b) { return a < b ? a : b; }

extern "C" void kernel_launch(void* const* d_in, const int* in_sizes, int n_in,
                              void* d_out, int out_size, void* d_ws, size_t ws_size,
                              hipStream_t stream) {
  const float* signal = (const float*)d_in[0];
  const int*   bc_idx = (const int*)d_in[1];
  const float* bc_w   = (const float*)d_in[2];
  const float* tmpl[3] = { (const float*)d_in[3], (const float*)d_in[5], (const float*)d_in[7] };
  const float* tb[3]   = { (const float*)d_in[4], (const float*)d_in[6], (const float*)d_in[8] };
  const float* Wd = (const float*)d_in[9];
  const float* bd = (const float*)d_in[10];
  float* outp = (float*)d_out;

  char* ws = (char*)d_ws;
  size_t off = 0;
  auto alloc = [&](size_t b) -> void* {
    size_t o = (off + 255) & ~(size_t)255; off = o + b; return (void*)(ws + o);
  };
  u16* sigbf = (u16*)alloc((size_t)V_N * 544 * 2);
  u16* outL0 = (u16*)alloc((size_t)V_PAD * 96 * 2);
  u16* outL1 = (u16*)alloc((size_t)V_PAD * 128 * 2);
  u16* outL2 = (u16*)alloc((size_t)V_PAD * 256 * 2);      // split hi|lo
  u16* trot  = (u16*)alloc((size_t)1024 * 21760 * 2);     // max over layers; reused for WdT
  float* gemmC = (float*)alloc((size_t)6 * V_PAD * 768 * 4); // split-K partials (127 MB max)
  size_t o2 = (off + 255) & ~(size_t)255;
  u16* interp = (u16*)(ws + o2);
  size_t interpElems = (ws_size > o2) ? (ws_size - o2) / 2 : 0;

  { int total4 = V_N * 544 / 4;
    cvt_kernel<<<dim3((total4 + 255) / 256), dim3(256), 0, stream>>>(signal, sigbf, total4); }

  const int TnA[3] = {96, 128, 128}, CcA[3] = {544, 96, 128};
  const int SplitA[3] = {6, 4, 4};
  u16* outs[3] = { outL0, outL1, outL2 };
  const u16* cursig = sigbf;
  for (int L = 0; L < 3; ++L) {
    const int Tn = TnA[L], Cc = CcA[L];
    const int K = 40 * Cc, N = 8 * Tn, C8 = Cc / 8, C4 = Cc / 4;
    const int nsplit = SplitA[L];
    const int kchunk = ((K / 64 + nsplit - 1) / nsplit) * 64;  // multiple of 64
    const size_t cstride = (size_t)V_PAD * N;
    { int total = N * 40 * C4;
      trot_kernel<<<dim3((total + 255) / 256), dim3(256), 0, stream>>>(tmpl[L], trot, Tn, Cc, C4, total); }
    long crl = (long)(interpElems / (size_t)K) & ~(long)255;
    int cr;
    if (crl >= (long)V_PAD) cr = V_PAD;                 // single dispatch (preferred)
    else { cr = (crl > 3584) ? 3584 : (int)crl; if (cr < 256) cr = 256; }
    const int ntn = N / 256;
    for (int v0 = 0; v0 < V_PAD; v0 += cr) {
      int rows = imin(cr, V_PAD - v0);
      int nv = imin(rows, V_N - v0);
      { int total = nv * 40 * C8;
        interp_kernel<<<dim3((total + 255) / 256), dim3(256), 0, stream>>>(
            cursig, Cc, C8, bc_idx, bc_w, interp, v0, K, total); }
      int ntm = rows / 256;
      gemm256<<<dim3(ntm * ntn * nsplit), dim3(512), 0, stream>>>(
          interp, K, trot, K, gemmC + (size_t)v0 * N, N, cstride, nullptr, nv, N, kchunk, K, ntm, ntn);
    }
    { int total = V_N * Tn;
      int ldo = (L == 2) ? 256 : ((L == 0) ? 96 : 128);
      amp_kernel<<<dim3((total + 255) / 256), dim3(256), 0, stream>>>(
          gemmC, cstride, nsplit, tb[L], outs[L], Tn, ldo, (L == 2) ? 1 : 0, total); }
    cursig = outs[L];
  }

  { int total = V_PAD * 128;
    wdt_kernel<<<dim3((total + 255) / 256), dim3(256), 0, stream>>>(Wd, trot, total); }
  gemm256<<<dim3(27 * 27), dim3(512), 0, stream>>>(
      outL2, 256, trot, 256, outp, V_N, 0, bd, V_N, V_N, 256, 256, 27, 27);
}

// Round 8
// 780.820 us; speedup vs baseline: 4.8947x; 1.0669x over previous
//
#include <hip/hip_runtime.h>

typedef unsigned short u16;
typedef unsigned int   u32;
typedef __bf16 bf16x8 __attribute__((ext_vector_type(8)));
typedef float  f32x4  __attribute__((ext_vector_type(4)));
typedef u32    u32x4  __attribute__((ext_vector_type(4)));
typedef u16    u16x4  __attribute__((ext_vector_type(4)));

#define V_N   6890
#define V_PAD 6912

__device__ __forceinline__ float bf2f(u32 h) {
  union { u32 u; float f; } c; c.u = h << 16; return c.f;
}
__device__ __forceinline__ u16 f2bf(float f) {
  union { float f; u32 u; } c; c.f = f;
  return (u16)((c.u + 0x7fffu + ((c.u >> 16) & 1u)) >> 16);
}
__device__ __forceinline__ void gload_lds16(const void* g, void* l) {
  __builtin_amdgcn_global_load_lds((const __attribute__((address_space(1))) void*)g,
                                   (__attribute__((address_space(3))) void*)l, 16, 0, 0);
}

// ---- f32 -> bf16 (vec4) ----
__global__ void cvt_kernel(const float* __restrict__ in, u16* __restrict__ out, int total4) {
  int g = blockIdx.x * 256 + threadIdx.x;
  if (g >= total4) return;
  f32x4 v = *(const f32x4*)(in + (size_t)g * 4);
  u16x4 o; o.x = f2bf(v.x); o.y = f2bf(v.y); o.z = f2bf(v.z); o.w = f2bf(v.w);
  *(u16x4*)(out + (size_t)g * 4) = o;
}

// ---- build rotated templates, bf16, B^T layout ----
__global__ void trot_kernel(const float* __restrict__ T, u16* __restrict__ out,
                            int Tn, int Cc, int C4, int total) {
  int g = blockIdx.x * 256 + threadIdx.x;
  if (g >= total) return;
  int c4 = g % C4; int q = g / C4;
  int a = q & 7; q >>= 3;
  int r = q % 5; q /= 5;
  int t = q % Tn; int o = q / Tn;
  f32x4 s = *(const f32x4*)(T + (size_t)((t * 5 + r) * 8 + ((a - o + 8) & 7)) * Cc + c4 * 4);
  u16x4 d; d.x = f2bf(s.x); d.y = f2bf(s.y); d.z = f2bf(s.z); d.w = f2bf(s.w);
  *(u16x4*)(out + ((size_t)(o * Tn + t) * 40 + (r * 8 + a)) * Cc + c4 * 4) = d;
}

// ---- barycentric gather+interp ----
__global__ void interp_kernel(const u16* __restrict__ sig, int Cc, int C8,
                              const int* __restrict__ idx, const float* __restrict__ w,
                              u16* __restrict__ out, int v0, int Kl, int total) {
  int g = blockIdx.x * 256 + threadIdx.x;
  if (g >= total) return;
  int q = g / C8, c8 = g - q * C8;
  int vr = q / 40, ra = q - vr * 40;
  size_t ib = ((size_t)(v0 + vr) * 40 + ra) * 3;
  int i0 = idx[ib], i1 = idx[ib + 1], i2 = idx[ib + 2];
  float w0 = w[ib], w1 = w[ib + 1], w2 = w[ib + 2];
  u32x4 s0 = *(const u32x4*)(sig + (size_t)i0 * Cc + c8 * 8);
  u32x4 s1 = *(const u32x4*)(sig + (size_t)i1 * Cc + c8 * 8);
  u32x4 s2 = *(const u32x4*)(sig + (size_t)i2 * Cc + c8 * 8);
  u32x4 o;
#pragma unroll
  for (int j = 0; j < 4; ++j) {
    float lo = w0 * bf2f(s0[j] & 0xffffu) + w1 * bf2f(s1[j] & 0xffffu) + w2 * bf2f(s2[j] & 0xffffu);
    float hi = w0 * bf2f(s0[j] >> 16)     + w1 * bf2f(s1[j] >> 16)     + w2 * bf2f(s2[j] >> 16);
    o[j] = (u32)f2bf(lo) | ((u32)f2bf(hi) << 16);
  }
  *(u32x4*)(out + (size_t)vr * Kl + ra * Cc + c8 * 8) = o;
}

// ---- split-K reduce + relu(+bias) + angular max; optional split-bf16 (hi|lo) output ----
__global__ void amp_kernel(const float* __restrict__ Cin, size_t cstride, int nsplit,
                           const float* __restrict__ bias, u16* __restrict__ out,
                           int Tn, int ldo, int split, int total) {
  int g = blockIdx.x * 256 + threadIdx.x;
  if (g >= total) return;
  int t = g % Tn, v = g / Tn;
  const float* row = Cin + (size_t)v * (8 * Tn) + t;
  float acc[8];
#pragma unroll
  for (int o = 0; o < 8; ++o) acc[o] = row[(size_t)o * Tn];
  for (int s = 1; s < nsplit; ++s) {
    row += cstride;
#pragma unroll
    for (int o = 0; o < 8; ++o) acc[o] += row[(size_t)o * Tn];
  }
  float b = bias[t];
  float m = acc[0] + b;
#pragma unroll
  for (int o = 1; o < 8; ++o) m = fmaxf(m, acc[o] + b);
  m = fmaxf(m, 0.f);
  u16 hi = f2bf(m);
  out[(size_t)v * ldo + t] = hi;
  if (split) out[(size_t)v * ldo + Tn + t] = f2bf(m - bf2f(hi));
}

// ---- Wd [128][V] f32 -> WdT split-bf16 [V_PAD][256] (hi | lo along k) ----
__global__ void wdt_kernel(const float* __restrict__ Wd, u16* __restrict__ out, int total) {
  int g = blockIdx.x * 256 + threadIdx.x;
  if (g >= total) return;
  int k = g & 127, n = g >> 7;
  float v = (n < V_N) ? Wd[(size_t)k * V_N + n] : 0.f;
  u16 hi = f2bf(v);
  out[(size_t)n * 256 + k] = hi;
  out[(size_t)n * 256 + 128 + k] = f2bf(v - bf2f(hi));
}

// ---- 256x256 bf16 GEMM, BK=64, 8 waves (2Mx4N), double-buffered LDS (128 KiB),
//      counted vmcnt(8) prefetch. 4-phase quadrant schedule, m201 placement:
//      per phase {reads; setprio MFMA cluster} with sched_barrier(0) ONLY at
//      s_barrier boundaries — compiler keeps fine-grained lgkmcnt WITHIN a
//      phase (R7 lesson), barriers create cross-wave read/MFMA overlap (T3/T5).
//      Verified XOR swizzle (conflicts=0), split-K, bijective XCD map.
//      __launch_bounds__(512,2): acc needs 128 regs; (512,4) spills (R4). ----
__global__ __launch_bounds__(512, 2) void gemm256(
    const u16* __restrict__ A, int lda,
    const u16* __restrict__ B, int ldb,
    float* __restrict__ C, int ldc, size_t cstride,
    const float* __restrict__ bias,
    int Mvalid, int Nvalid, int kchunk, int Ktot,
    int ntm, int ntn) {
  __shared__ __align__(16) u16 lA[2][256 * 64];
  __shared__ __align__(16) u16 lB[2][256 * 64];
  const int tid = threadIdx.x;
  const int w = tid >> 6, l = tid & 63;

  // bijective XCD chunking (m204)
  const int nb = gridDim.x, bid = blockIdx.x;
  const int q = nb >> 3, r = nb & 7;
  const int xcd = bid & 7, ii = bid >> 3;
  const int vb = (xcd < r ? xcd * (q + 1) : r * (q + 1) + (xcd - r) * q) + ii;
  const int per = ntm * ntn;
  const int s = vb / per;
  const int rem = vb - s * per;
  const int tm = rem / ntn, tn = rem - tm * ntn;
  const int kb = s * kchunk;
  int ke = kb + kchunk; if (ke > Ktot) ke = Ktot;
  const int nt = (ke - kb + 63) >> 6;
  float* Cb = C + (size_t)s * cstride;

  const u16* Ab = A + (size_t)(tm * 256) * lda + kb;
  const u16* Bb = B + (size_t)(tn * 256) * ldb + kb;

  // staging: linear LDS dest (wave-uniform base + lane*16B), pre-swizzled global col
  const int srow = tid >> 3;                                  // 0..63 (+i*64)
  const int scol = (((l & 7) ^ (srow & 7)) << 3);             // elements
  u16* laBase = &lA[0][0];
  u16* lbBase = &lB[0][0];

  auto STAGE = [&](int buf, int k0) {
    const u16* ga = Ab + (size_t)srow * lda + k0 + scol;
    const u16* gb = Bb + (size_t)srow * ldb + k0 + scol;
    u16* la = laBase + buf * (256 * 64) + w * 512;
    u16* lb = lbBase + buf * (256 * 64) + w * 512;
#pragma unroll
    for (int i = 0; i < 4; ++i) {
      gload_lds16(ga + (size_t)(i * 64) * lda, la + i * 4096);
      gload_lds16(gb + (size_t)(i * 64) * ldb, lb + i * 4096);
    }
  };

  f32x4 acc[8][4];
#pragma unroll
  for (int i = 0; i < 8; ++i)
#pragma unroll
    for (int j = 0; j < 4; ++j) acc[i][j] = (f32x4){0.f, 0.f, 0.f, 0.f};

  const int wm = w >> 2, wn = w & 3;
  const int aoffbase = (wm * 128 + (l & 15)) * 64;
  const int boffbase = (wn * 64 + (l & 15)) * 64;
  const int ksel = l >> 4, swz = l & 7;
  const int kc0 = ((ksel ^ swz) << 3);          // kk=0 chunk (swizzled)
  const int kc1 = (((4 + ksel) ^ swz) << 3);    // kk=1 chunk (swizzled)

  STAGE(0, 0);
  int cur = 0;
  for (int t = 0; t < nt; ++t) {
    if (t + 1 < nt) STAGE(cur ^ 1, (t + 1) * 64);
    __builtin_amdgcn_sched_barrier(0);
    if (t + 1 < nt) { asm volatile("s_waitcnt vmcnt(8)" ::: "memory"); }
    else            { asm volatile("s_waitcnt vmcnt(0)" ::: "memory"); }
    __builtin_amdgcn_s_barrier();
    __builtin_amdgcn_sched_barrier(0);
    const u16* lab = laBase + cur * (256 * 64);
    const u16* lbb = lbBase + cur * (256 * 64);

    bf16x8 af0[4], af1[4], bf0[4], bf1[4];
    // ---- P0: 12 ds_reads + 16 MFMA: (m0-3) x (n0-1) ----
#pragma unroll
    for (int mi = 0; mi < 4; ++mi) {
      af0[mi] = *(const bf16x8*)&lab[aoffbase + mi * 1024 + kc0];
      af1[mi] = *(const bf16x8*)&lab[aoffbase + mi * 1024 + kc1];
    }
#pragma unroll
    for (int ni = 0; ni < 2; ++ni) {
      bf0[ni] = *(const bf16x8*)&lbb[boffbase + ni * 1024 + kc0];
      bf1[ni] = *(const bf16x8*)&lbb[boffbase + ni * 1024 + kc1];
    }
    __builtin_amdgcn_s_setprio(1);
#pragma unroll
    for (int mi = 0; mi < 4; ++mi)
#pragma unroll
      for (int ni = 0; ni < 2; ++ni) {
        acc[mi][ni] = __builtin_amdgcn_mfma_f32_16x16x32_bf16(af0[mi], bf0[ni], acc[mi][ni], 0, 0, 0);
        acc[mi][ni] = __builtin_amdgcn_mfma_f32_16x16x32_bf16(af1[mi], bf1[ni], acc[mi][ni], 0, 0, 0);
      }
    __builtin_amdgcn_s_setprio(0);
    __builtin_amdgcn_sched_barrier(0);
    __builtin_amdgcn_s_barrier();
    __builtin_amdgcn_sched_barrier(0);
    // ---- P1: 4 ds_reads + 16 MFMA: (m0-3) x (n2-3) ----
#pragma unroll
    for (int ni = 2; ni < 4; ++ni) {
      bf0[ni] = *(const bf16x8*)&lbb[boffbase + ni * 1024 + kc0];
      bf1[ni] = *(const bf16x8*)&lbb[boffbase + ni * 1024 + kc1];
    }
    __builtin_amdgcn_s_setprio(1);
#pragma unroll
    for (int mi = 0; mi < 4; ++mi)
#pragma unroll
      for (int ni = 2; ni < 4; ++ni) {
        acc[mi][ni] = __builtin_amdgcn_mfma_f32_16x16x32_bf16(af0[mi], bf0[ni], acc[mi][ni], 0, 0, 0);
        acc[mi][ni] = __builtin_amdgcn_mfma_f32_16x16x32_bf16(af1[mi], bf1[ni], acc[mi][ni], 0, 0, 0);
      }
    __builtin_amdgcn_s_setprio(0);
    __builtin_amdgcn_sched_barrier(0);
    __builtin_amdgcn_s_barrier();
    __builtin_amdgcn_sched_barrier(0);
    // ---- P2: 8 ds_reads + 16 MFMA: (m4-7) x (n0-1) ----
#pragma unroll
    for (int mi = 0; mi < 4; ++mi) {
      af0[mi] = *(const bf16x8*)&lab[aoffbase + (4 + mi) * 1024 + kc0];
      af1[mi] = *(const bf16x8*)&lab[aoffbase + (4 + mi) * 1024 + kc1];
    }
    __builtin_amdgcn_s_setprio(1);
#pragma unroll
    for (int mi = 0; mi < 4; ++mi)
#pragma unroll
      for (int ni = 0; ni < 2; ++ni) {
        acc[4 + mi][ni] = __builtin_amdgcn_mfma_f32_16x16x32_bf16(af0[mi], bf0[ni], acc[4 + mi][ni], 0, 0, 0);
        acc[4 + mi][ni] = __builtin_amdgcn_mfma_f32_16x16x32_bf16(af1[mi], bf1[ni], acc[4 + mi][ni], 0, 0, 0);
      }
    __builtin_amdgcn_s_setprio(0);
    __builtin_amdgcn_sched_barrier(0);
    __builtin_amdgcn_s_barrier();
    __builtin_amdgcn_sched_barrier(0);
    // ---- P3: 0 ds_reads + 16 MFMA: (m4-7) x (n2-3) ----
    __builtin_amdgcn_s_setprio(1);
#pragma unroll
    for (int mi = 0; mi < 4; ++mi)
#pragma unroll
      for (int ni = 2; ni < 4; ++ni) {
        acc[4 + mi][ni] = __builtin_amdgcn_mfma_f32_16x16x32_bf16(af0[mi], bf0[ni], acc[4 + mi][ni], 0, 0, 0);
        acc[4 + mi][ni] = __builtin_amdgcn_mfma_f32_16x16x32_bf16(af1[mi], bf1[ni], acc[4 + mi][ni], 0, 0, 0);
      }
    __builtin_amdgcn_s_setprio(0);
    __builtin_amdgcn_sched_barrier(0);
    __builtin_amdgcn_s_barrier();   // end of tile: buf safe to overwrite next iter
    cur ^= 1;
  }

  const int row0 = tm * 256 + wm * 128 + ((l >> 4) << 2);
  const int col0 = tn * 256 + wn * 64 + (l & 15);
#pragma unroll
  for (int mi = 0; mi < 8; ++mi) {
#pragma unroll
    for (int j = 0; j < 4; ++j) {
      int grow = row0 + mi * 16 + j;
      if (grow < Mvalid) {
#pragma unroll
        for (int ni = 0; ni < 4; ++ni) {
          int gcol = col0 + ni * 16;
          if (gcol < Nvalid) {
            float vv = acc[mi][ni][j];
            if (bias) vv += bias[gcol];
            Cb[(size_t)grow * ldc + gcol] = vv;
          }
        }
      }
    }
  }
}

static inline int imin(int a, int b) { return a < b ? a : b; }

extern "C" void kernel_launch(void* const* d_in, const int* in_sizes, int n_in,
                              void* d_out, int out_size, void* d_ws, size_t ws_size,
                              hipStream_t stream) {
  const float* signal = (const float*)d_in[0];
  const int*   bc_idx = (const int*)d_in[1];
  const float* bc_w   = (const float*)d_in[2];
  const float* tmpl[3] = { (const float*)d_in[3], (const float*)d_in[5], (const float*)d_in[7] };
  const float* tb[3]   = { (const float*)d_in[4], (const float*)d_in[6], (const float*)d_in[8] };
  const float* Wd = (const float*)d_in[9];
  const float* bd = (const float*)d_in[10];
  float* outp = (float*)d_out;

  char* ws = (char*)d_ws;
  size_t off = 0;
  auto alloc = [&](size_t b) -> void* {
    size_t o = (off + 255) & ~(size_t)255; off = o + b; return (void*)(ws + o);
  };
  u16* sigbf = (u16*)alloc((size_t)V_N * 544 * 2);
  u16* outL0 = (u16*)alloc((size_t)V_PAD * 96 * 2);
  u16* outL1 = (u16*)alloc((size_t)V_PAD * 128 * 2);
  u16* outL2 = (u16*)alloc((size_t)V_PAD * 256 * 2);      // split hi|lo
  u16* trot  = (u16*)alloc((size_t)1024 * 21760 * 2);     // max over layers; reused for WdT
  float* gemmC = (float*)alloc((size_t)6 * V_PAD * 768 * 4); // split-K partials (127 MB max)
  size_t o2 = (off + 255) & ~(size_t)255;
  u16* interp = (u16*)(ws + o2);
  size_t interpElems = (ws_size > o2) ? (ws_size - o2) / 2 : 0;

  { int total4 = V_N * 544 / 4;
    cvt_kernel<<<dim3((total4 + 255) / 256), dim3(256), 0, stream>>>(signal, sigbf, total4); }

  const int TnA[3] = {96, 128, 128}, CcA[3] = {544, 96, 128};
  const int SplitA[3] = {6, 4, 4};
  const int CrA[3] = {3584, V_PAD, V_PAD};   // L0 chunked: 252-block rounds + L3-hot interp
  u16* outs[3] = { outL0, outL1, outL2 };
  const u16* cursig = sigbf;
  for (int L = 0; L < 3; ++L) {
    const int Tn = TnA[L], Cc = CcA[L];
    const int K = 40 * Cc, N = 8 * Tn, C8 = Cc / 8, C4 = Cc / 4;
    const int nsplit = SplitA[L];
    const int kchunk = ((K / 64 + nsplit - 1) / nsplit) * 64;  // multiple of 64
    const size_t cstride = (size_t)V_PAD * N;
    { int total = N * 40 * C4;
      trot_kernel<<<dim3((total + 255) / 256), dim3(256), 0, stream>>>(tmpl[L], trot, Tn, Cc, C4, total); }
    long crl = (long)(interpElems / (size_t)K) & ~(long)255;
    int cr = (crl > (long)CrA[L]) ? CrA[L] : (int)crl;
    if (cr < 256) cr = 256;
    const int ntn = N / 256;
    for (int v0 = 0; v0 < V_PAD; v0 += cr) {
      int rows = imin(cr, V_PAD - v0);
      int nv = imin(rows, V_N - v0);
      { int total = nv * 40 * C8;
        interp_kernel<<<dim3((total + 255) / 256), dim3(256), 0, stream>>>(
            cursig, Cc, C8, bc_idx, bc_w, interp, v0, K, total); }
      int ntm = rows / 256;
      gemm256<<<dim3(ntm * ntn * nsplit), dim3(512), 0, stream>>>(
          interp, K, trot, K, gemmC + (size_t)v0 * N, N, cstride, nullptr, nv, N, kchunk, K, ntm, ntn);
    }
    { int total = V_N * Tn;
      int ldo = (L == 2) ? 256 : ((L == 0) ? 96 : 128);
      amp_kernel<<<dim3((total + 255) / 256), dim3(256), 0, stream>>>(
          gemmC, cstride, nsplit, tb[L], outs[L], Tn, ldo, (L == 2) ? 1 : 0, total); }
    cursig = outs[L];
  }

  { int total = V_PAD * 128;
    wdt_kernel<<<dim3((total + 255) / 256), dim3(256), 0, stream>>>(Wd, trot, total); }
  gemm256<<<dim3(27 * 27), dim3(512), 0, stream>>>(
      outL2, 256, trot, 256, outp, V_N, 0, bd, V_N, V_N, 256, 256, 27, 27);
}

// Round 9
// 637.791 us; speedup vs baseline: 5.9923x; 1.2243x over previous
//
#include <hip/hip_runtime.h>

typedef unsigned short u16;
typedef unsigned int   u32;
typedef __bf16 bf16x8 __attribute__((ext_vector_type(8)));
typedef float  f32x4  __attribute__((ext_vector_type(4)));
typedef u32    u32x4  __attribute__((ext_vector_type(4)));
typedef u32    u32x2  __attribute__((ext_vector_type(2)));
typedef u16    u16x4  __attribute__((ext_vector_type(4)));

#define V_N   6890
#define V_PAD 6912
#define SQ2H  0.70710678118654752f

__device__ __forceinline__ float bf2f(u32 h) {
  union { u32 u; float f; } c; c.u = h << 16; return c.f;
}
__device__ __forceinline__ u16 f2bf(float f) {
  union { float f; u32 u; } c; c.f = f;
  return (u16)((c.u + 0x7fffu + ((c.u >> 16) & 1u)) >> 16);
}
__device__ __forceinline__ u32 pk(float lo, float hi) {
  return (u32)f2bf(lo) | ((u32)f2bf(hi) << 16);
}
__device__ __forceinline__ void gload_lds16(const void* g, void* l) {
  __builtin_amdgcn_global_load_lds((const __attribute__((address_space(1))) void*)g,
                                   (__attribute__((address_space(3))) void*)l, 16, 0, 0);
}

// rfft8: X[k] = sum_a x[a] e^{-2pi i k a/8}; returns Z0, (Re,Im) k=1..3, Z4.
__device__ __forceinline__ void rfft8(const float* x, float& Z0, float& Re1, float& Im1,
                                      float& Re2, float& Im2, float& Re3, float& Im3, float& Z4) {
  float s04 = x[0] + x[4], d04 = x[0] - x[4];
  float s26 = x[2] + x[6], d26 = x[2] - x[6];
  float s15 = x[1] + x[5], d15 = x[1] - x[5];
  float s37 = x[3] + x[7], d37 = x[3] - x[7];
  float e = s04 + s26, f = s15 + s37;
  Z0 = e + f; Z4 = e - f;
  Re2 = s04 - s26; Im2 = s37 - s15;
  float t1 = SQ2H * (d15 - d37), t2 = SQ2H * (d15 + d37);
  Re1 = d04 + t1; Re3 = d04 - t1;
  Im1 = -(t2 + d26); Im3 = d26 - t2;
}

// ---- f32 -> bf16 (vec4) ----
__global__ void cvt_kernel(const float* __restrict__ in, u16* __restrict__ out, int total4) {
  int g = blockIdx.x * 256 + threadIdx.x;
  if (g >= total4) return;
  f32x4 v = *(const f32x4*)(in + (size_t)g * 4);
  u16x4 o; o.x = f2bf(v.x); o.y = f2bf(v.y); o.z = f2bf(v.z); o.w = f2bf(v.w);
  *(u16x4*)(out + (size_t)g * 4) = o;
}

// ---- template FFT: build frequency-domain B groups (B0|B1|B2|B3|B4), scaled 1/8 (bins 1-3: 1/4) ----
__global__ void trot_fft_kernel(const float* __restrict__ T, u16* __restrict__ B,
                                int Tn, int Cc, int C4, int K0pad, int K1, int total) {
  int g = blockIdx.x * 256 + threadIdx.x;
  if (g >= total) return;
  int c4 = g % C4; int q = g / C4;
  int r = q % 5; int t = q / 5;
  float hs[8][4];
#pragma unroll
  for (int a = 0; a < 8; ++a) {
    f32x4 va = *(const f32x4*)(T + ((size_t)((t * 5 + r) * 8 + a)) * Cc + c4 * 4);
#pragma unroll
    for (int j = 0; j < 4; ++j) hs[a][j] = va[j];
  }
  float Z0[4], Z4[4], Re[3][4], Im[3][4];
#pragma unroll
  for (int ch = 0; ch < 4; ++ch) {
    float x[8];
#pragma unroll
    for (int a = 0; a < 8; ++a) x[a] = hs[a][ch];
    float z0, r1, i1, r2, i2, r3, i3, z4;
    rfft8(x, z0, r1, i1, r2, i2, r3, i3, z4);
    Z0[ch] = z0 * 0.125f; Z4[ch] = z4 * 0.125f;
    Re[0][ch] = r1 * 0.25f; Im[0][ch] = i1 * 0.25f;
    Re[1][ch] = r2 * 0.25f; Im[1][ch] = i2 * 0.25f;
    Re[2][ch] = r3 * 0.25f; Im[2][ch] = i3 * 0.25f;
  }
  int cb = c4 * 4;
  u32x2 w0v; w0v[0] = pk(Z0[0], Z0[1]); w0v[1] = pk(Z0[2], Z0[3]);
  *(u32x2*)(B + (size_t)t * K0pad + r * Cc + cb) = w0v;
  size_t bo1 = (size_t)Tn * K0pad;
  size_t binSz = (size_t)2 * Tn * K1;
  int off = ((r * Cc + cb) << 1);
#pragma unroll
  for (int k = 0; k < 3; ++k) {
    u32x4 wr, wi;
#pragma unroll
    for (int j = 0; j < 4; ++j) {
      wr[j] = pk(Re[k][j], Im[k][j]);
      wi[j] = pk(-Im[k][j], Re[k][j]);
    }
    *(u32x4*)(B + bo1 + k * binSz + (size_t)t * K1 + off) = wr;
    *(u32x4*)(B + bo1 + k * binSz + (size_t)(Tn + t) * K1 + off) = wi;
  }
  u32x2 w4v; w4v[0] = pk(Z4[0], Z4[1]); w4v[1] = pk(Z4[2], Z4[3]);
  *(u32x2*)(B + bo1 + 3 * binSz + (size_t)t * K0pad + r * Cc + cb) = w4v;
}

// ---- zero the K-pad columns of B0 and B4 (A-pad garbage then cannot contribute) ----
__global__ void bpad_kernel(u16* __restrict__ B, int K0pad, int pad, size_t b4off, int total) {
  int g = blockIdx.x * 256 + threadIdx.x;
  if (g >= total) return;
  int p = g % pad; int t = g / pad;
  size_t o = (size_t)t * K0pad + (K0pad - pad) + p;
  B[o] = 0;
  B[b4off + o] = 0;
}

// ---- barycentric gather + interp + rfft8 over angular axis; writes A_hat sections ----
__global__ void interp_fft_kernel(const u16* __restrict__ sig, int Cc, int C8,
                                  const int* __restrict__ idx, const float* __restrict__ wgt,
                                  u16* __restrict__ out, int v0, int Kpad, int K0pad, int K1,
                                  int total) {
  int g = blockIdx.x * 256 + threadIdx.x;
  if (g >= total) return;
  int c8 = g % C8; int q = g / C8;
  int r = q % 5; int vr = q / 5;
  size_t ib = ((size_t)((v0 + vr) * 5 + r)) * 24;
  float xs[8][8];
#pragma unroll
  for (int a = 0; a < 8; ++a) {
    int i0 = idx[ib + a * 3], i1 = idx[ib + a * 3 + 1], i2 = idx[ib + a * 3 + 2];
    float w0 = wgt[ib + a * 3], w1 = wgt[ib + a * 3 + 1], w2 = wgt[ib + a * 3 + 2];
    u32x4 s0 = *(const u32x4*)(sig + (size_t)i0 * Cc + c8 * 8);
    u32x4 s1 = *(const u32x4*)(sig + (size_t)i1 * Cc + c8 * 8);
    u32x4 s2 = *(const u32x4*)(sig + (size_t)i2 * Cc + c8 * 8);
#pragma unroll
    for (int j = 0; j < 4; ++j) {
      xs[a][2 * j]     = w0 * bf2f(s0[j] & 0xffffu) + w1 * bf2f(s1[j] & 0xffffu) + w2 * bf2f(s2[j] & 0xffffu);
      xs[a][2 * j + 1] = w0 * bf2f(s0[j] >> 16)     + w1 * bf2f(s1[j] >> 16)     + w2 * bf2f(s2[j] >> 16);
    }
  }
  float Z0[8], Z4[8], Re1[8], Im1[8], Re2[8], Im2[8], Re3[8], Im3[8];
#pragma unroll
  for (int ch = 0; ch < 8; ++ch) {
    float x[8];
#pragma unroll
    for (int a = 0; a < 8; ++a) x[a] = xs[a][ch];
    rfft8(x, Z0[ch], Re1[ch], Im1[ch], Re2[ch], Im2[ch], Re3[ch], Im3[ch], Z4[ch]);
  }
  size_t rowb = (size_t)vr * Kpad;
  int cb = c8 * 8;
  u32x4 a0, a4;
#pragma unroll
  for (int p = 0; p < 4; ++p) {
    a0[p] = pk(Z0[2 * p], Z0[2 * p + 1]);
    a4[p] = pk(Z4[2 * p], Z4[2 * p + 1]);
  }
  *(u32x4*)(out + rowb + r * Cc + cb) = a0;
  *(u32x4*)(out + rowb + K0pad + 3 * K1 + r * Cc + cb) = a4;
  int off1 = K0pad + ((r * Cc + cb) << 1);
  u32x4 wa, wb;
#pragma unroll
  for (int j = 0; j < 4; ++j) { wa[j] = pk(Re1[j], Im1[j]); wb[j] = pk(Re1[4 + j], Im1[4 + j]); }
  *(u32x4*)(out + rowb + off1) = wa;
  *(u32x4*)(out + rowb + off1 + 8) = wb;
#pragma unroll
  for (int j = 0; j < 4; ++j) { wa[j] = pk(Re2[j], Im2[j]); wb[j] = pk(Re2[4 + j], Im2[4 + j]); }
  *(u32x4*)(out + rowb + off1 + K1) = wa;
  *(u32x4*)(out + rowb + off1 + K1 + 8) = wb;
#pragma unroll
  for (int j = 0; j < 4; ++j) { wa[j] = pk(Re3[j], Im3[j]); wb[j] = pk(Re3[4 + j], Im3[4 + j]); }
  *(u32x4*)(out + rowb + off1 + 2 * K1) = wa;
  *(u32x4*)(out + rowb + off1 + 2 * K1 + 8) = wb;
}

// ---- split-K reduce + 8-point iFFT + relu(+bias) + angular max; optional split-bf16 out ----
__global__ void amp_fft(const float* __restrict__ Cin, size_t cstride,
                        const float* __restrict__ bias, u16* __restrict__ out,
                        int Tn, int ldo, int split,
                        int ns0, int ns1, int ns2, int ns3, int ns4, int total) {
  int g = blockIdx.x * 256 + threadIdx.x;
  if (g >= total) return;
  int t = g % Tn, v = g / Tn;
  const int nsA[8] = {ns0, ns1, ns1, ns2, ns2, ns3, ns3, ns4};
  float sec[8];
  size_t base = (size_t)v * (8 * Tn) + t;
#pragma unroll
  for (int s = 0; s < 8; ++s) {
    const float* p = Cin + base + s * Tn;
    float a = p[0];
    for (int k = 1; k < nsA[s]; ++k) a += p[(size_t)k * cstride];
    sec[s] = a;
  }
  const float Ct[8] = {1.f, SQ2H, 0.f, -SQ2H, -1.f, -SQ2H, 0.f, SQ2H};
  const float St[8] = {0.f, SQ2H, 1.f, SQ2H, 0.f, -SQ2H, -1.f, -SQ2H};
  float m;
#pragma unroll
  for (int o = 0; o < 8; ++o) {
    float val = sec[0] + ((o & 1) ? -sec[7] : sec[7])
      + sec[1] * Ct[o]           - sec[2] * St[o]
      + sec[3] * Ct[(2 * o) & 7] - sec[4] * St[(2 * o) & 7]
      + sec[5] * Ct[(3 * o) & 7] - sec[6] * St[(3 * o) & 7];
    m = (o == 0) ? val : fmaxf(m, val);
  }
  m = fmaxf(m + bias[t], 0.f);
  u16 hi = f2bf(m);
  out[(size_t)v * ldo + t] = hi;
  if (split) out[(size_t)v * ldo + Tn + t] = f2bf(m - bf2f(hi));
}

// ---- Wd [128][V] f32 -> WdT split-bf16 [V_PAD][256] (hi | lo along k) ----
__global__ void wdt_kernel(const float* __restrict__ Wd, u16* __restrict__ out, int total) {
  int g = blockIdx.x * 256 + threadIdx.x;
  if (g >= total) return;
  int k = g & 127, n = g >> 7;
  float v = (n < V_N) ? Wd[(size_t)k * V_N + n] : 0.f;
  u16 hi = f2bf(v);
  out[(size_t)n * 256 + k] = hi;
  out[(size_t)n * 256 + 128 + k] = f2bf(v - bf2f(hi));
}

// ---- grouped 256x256 bf16 GEMM (R7-proven body): per-block group table resolves
//      {A col-offset, B buffer, K, split-K chunk, N-tiles, valid-N, C col-offset}.
//      BK=64, 8 waves, dbuf LDS, counted vmcnt(8), XOR swizzle, setprio, XCD map. ----
struct GTab {
  int start[6];
  int aOff[5];
  int bOff[5];
  int cOff[5];
  int Kg[5];
  int kch[5];
  int ntn[5];
  int Nv[5];
};

__global__ __launch_bounds__(512, 2) void gemm_grp(
    const u16* __restrict__ A, int lda, const u16* __restrict__ Bbase,
    float* __restrict__ C, int ldc, size_t cstride,
    const float* __restrict__ bias, int Mvalid, int ntm, int nG, GTab tb) {
  __shared__ __align__(16) u16 lA[2][256 * 64];
  __shared__ __align__(16) u16 lB[2][256 * 64];
  const int tid = threadIdx.x;
  const int w = tid >> 6, l = tid & 63;

  const int nb = gridDim.x, bid = blockIdx.x;
  const int qq = nb >> 3, rr = nb & 7;
  const int xcd = bid & 7, ii = bid >> 3;
  const int vb = (xcd < rr ? xcd * (qq + 1) : rr * (qq + 1) + (xcd - rr) * qq) + ii;

  int gI = 0;
#pragma unroll
  for (int k = 1; k < 5; ++k) if (k < nG && vb >= tb.start[k]) gI = k;
  const int local = vb - tb.start[gI];
  const int ntnG = tb.ntn[gI];
  const int per = ntm * ntnG;
  const int s = local / per;
  const int rem = local - s * per;
  const int tm = rem / ntnG, tn = rem - tm * ntnG;
  const int Kg = tb.Kg[gI];
  const int kb = s * tb.kch[gI];
  int ke = kb + tb.kch[gI]; if (ke > Kg) ke = Kg;
  const int nt = (ke - kb + 63) >> 6;
  const int Nv = tb.Nv[gI];
  const int cO = tb.cOff[gI];
  const int ldb = Kg;
  float* Cb = C + (size_t)s * cstride;

  const u16* Ab = A + (size_t)(tm * 256) * lda + tb.aOff[gI] + kb;
  const u16* Bb = Bbase + tb.bOff[gI] + (size_t)(tn * 256) * ldb + kb;

  const int srow = tid >> 3;
  const int scol = (((l & 7) ^ (srow & 7)) << 3);
  u16* laBase = &lA[0][0];
  u16* lbBase = &lB[0][0];

  auto STAGE = [&](int buf, int k0) {
    const u16* ga = Ab + (size_t)srow * lda + k0 + scol;
    const u16* gb = Bb + (size_t)srow * ldb + k0 + scol;
    u16* la = laBase + buf * (256 * 64) + w * 512;
    u16* lb = lbBase + buf * (256 * 64) + w * 512;
#pragma unroll
    for (int i = 0; i < 4; ++i) {
      gload_lds16(ga + (size_t)(i * 64) * lda, la + i * 4096);
      gload_lds16(gb + (size_t)(i * 64) * ldb, lb + i * 4096);
    }
  };

  f32x4 acc[8][4];
#pragma unroll
  for (int i = 0; i < 8; ++i)
#pragma unroll
    for (int j = 0; j < 4; ++j) acc[i][j] = (f32x4){0.f, 0.f, 0.f, 0.f};

  const int wm = w >> 2, wn = w & 3;
  const int aoffbase = (wm * 128 + (l & 15)) * 64;
  const int boffbase = (wn * 64 + (l & 15)) * 64;
  const int ksel = l >> 4, swz = l & 7;
  const int kc0 = ((ksel ^ swz) << 3);
  const int kc1 = (((4 + ksel) ^ swz) << 3);

  STAGE(0, 0);
  int cur = 0;
  for (int t = 0; t < nt; ++t) {
    if (t + 1 < nt) STAGE(cur ^ 1, (t + 1) * 64);
    __builtin_amdgcn_sched_barrier(0);
    if (t + 1 < nt) { asm volatile("s_waitcnt vmcnt(8)" ::: "memory"); }
    else            { asm volatile("s_waitcnt vmcnt(0)" ::: "memory"); }
    __builtin_amdgcn_s_barrier();
    __builtin_amdgcn_sched_barrier(0);
    const u16* lab = laBase + cur * (256 * 64);
    const u16* lbb = lbBase + cur * (256 * 64);
#pragma unroll
    for (int kk = 0; kk < 2; ++kk) {
      const int kc = kk ? kc1 : kc0;
      bf16x8 bfr[4];
#pragma unroll
      for (int ni = 0; ni < 4; ++ni)
        bfr[ni] = *(const bf16x8*)&lbb[boffbase + ni * 1024 + kc];
#pragma unroll
      for (int mh = 0; mh < 2; ++mh) {
        bf16x8 afr[4];
#pragma unroll
        for (int mi = 0; mi < 4; ++mi)
          afr[mi] = *(const bf16x8*)&lab[aoffbase + (mh * 4 + mi) * 1024 + kc];
        __builtin_amdgcn_s_setprio(1);
#pragma unroll
        for (int mi = 0; mi < 4; ++mi)
#pragma unroll
          for (int ni = 0; ni < 4; ++ni)
            acc[mh * 4 + mi][ni] =
                __builtin_amdgcn_mfma_f32_16x16x32_bf16(afr[mi], bfr[ni], acc[mh * 4 + mi][ni], 0, 0, 0);
        __builtin_amdgcn_s_setprio(0);
      }
    }
    __builtin_amdgcn_sched_barrier(0);
    __builtin_amdgcn_s_barrier();
    cur ^= 1;
  }

  const int row0 = tm * 256 + wm * 128 + ((l >> 4) << 2);
  const int col0 = tn * 256 + wn * 64 + (l & 15);
#pragma unroll
  for (int mi = 0; mi < 8; ++mi) {
#pragma unroll
    for (int j = 0; j < 4; ++j) {
      int grow = row0 + mi * 16 + j;
      if (grow < Mvalid) {
#pragma unroll
        for (int ni = 0; ni < 4; ++ni) {
          int gcol = col0 + ni * 16;
          if (gcol < Nv) {
            float vv = acc[mi][ni][j];
            int gc = cO + gcol;
            if (bias) vv += bias[gc];
            Cb[(size_t)grow * ldc + gc] = vv;
          }
        }
      }
    }
  }
}

static inline int imin(int a, int b) { return a < b ? a : b; }

extern "C" void kernel_launch(void* const* d_in, const int* in_sizes, int n_in,
                              void* d_out, int out_size, void* d_ws, size_t ws_size,
                              hipStream_t stream) {
  const float* signal = (const float*)d_in[0];
  const int*   bc_idx = (const int*)d_in[1];
  const float* bc_w   = (const float*)d_in[2];
  const float* tmpl[3] = { (const float*)d_in[3], (const float*)d_in[5], (const float*)d_in[7] };
  const float* tb[3]   = { (const float*)d_in[4], (const float*)d_in[6], (const float*)d_in[8] };
  const float* Wd = (const float*)d_in[9];
  const float* bd = (const float*)d_in[10];
  float* outp = (float*)d_out;

  char* ws = (char*)d_ws;
  size_t off = 0;
  auto alloc = [&](size_t b) -> void* {
    size_t o = (off + 255) & ~(size_t)255; off = o + b; return (void*)(ws + o);
  };
  u16* sigbf = (u16*)alloc((size_t)V_N * 544 * 2);
  u16* outL0 = (u16*)alloc((size_t)V_PAD * 96 * 2);
  u16* outL1 = (u16*)alloc((size_t)V_PAD * 128 * 2);
  u16* outL2 = (u16*)alloc((size_t)V_PAD * 256 * 2);       // split hi|lo
  u16* trot  = (u16*)alloc((size_t)8 * 1024 * 1024 * 2);   // B_hat (max 7.3MB) / WdT; +OOB margin
  float* gemmC = (float*)alloc((size_t)4 * V_PAD * 1024 * 4); // split-K partials (113MB; L0 5x768 fits)
  size_t o2 = (off + 255) & ~(size_t)255;
  u16* interp = (u16*)(ws + o2);
  size_t interpElems = (ws_size > o2) ? (ws_size - o2) / 2 : 0;

  { int total4 = V_N * 544 / 4;
    cvt_kernel<<<dim3((total4 + 255) / 256), dim3(256), 0, stream>>>(signal, sigbf, total4); }

  const int TnA[3] = {96, 128, 128}, CcA[3] = {544, 96, 128};
  const int nsTab[3][5] = {{2,5,5,4,2},{3,4,4,4,3},{3,4,4,4,3}};
  const int CrA[3] = {3584, V_PAD, V_PAD};
  u16* outs[3] = { outL0, outL1, outL2 };
  const u16* cursig = sigbf;
  for (int L = 0; L < 3; ++L) {
    const int Tn = TnA[L], Cc = CcA[L];
    const int C8 = Cc / 8, C4 = Cc / 4;
    const int K0 = 5 * Cc, K0pad = ((K0 + 63) / 64) * 64;
    const int K1 = 10 * Cc;                     // 5440/960/1280 — all %64==0
    const int Kpad = 2 * K0pad + 3 * K1;
    const int N = 8 * Tn;
    const int* ns = nsTab[L];
    const size_t cstride = (size_t)V_PAD * N;

    { int total = Tn * 5 * C4;
      trot_fft_kernel<<<dim3((total + 255) / 256), dim3(256), 0, stream>>>(
          tmpl[L], trot, Tn, Cc, C4, K0pad, K1, total); }
    int pad = K0pad - K0;
    if (pad > 0) {
      int total = Tn * pad;
      size_t b4off = (size_t)Tn * K0pad + (size_t)6 * Tn * K1;
      bpad_kernel<<<dim3((total + 255) / 256), dim3(256), 0, stream>>>(trot, K0pad, pad, b4off, total);
    }

    GTab tg;
    int Kg5[5] = {K0pad, K1, K1, K1, K0pad};
    int Ng5[5] = {Tn, 2 * Tn, 2 * Tn, 2 * Tn, Tn};
    tg.aOff[0] = 0; tg.aOff[1] = K0pad; tg.aOff[2] = K0pad + K1;
    tg.aOff[3] = K0pad + 2 * K1; tg.aOff[4] = K0pad + 3 * K1;
    tg.bOff[0] = 0; tg.bOff[1] = Tn * K0pad;
    tg.bOff[2] = Tn * K0pad + 2 * Tn * K1;
    tg.bOff[3] = Tn * K0pad + 4 * Tn * K1;
    tg.bOff[4] = Tn * K0pad + 6 * Tn * K1;
    tg.cOff[0] = 0; tg.cOff[1] = Tn; tg.cOff[2] = 3 * Tn; tg.cOff[3] = 5 * Tn; tg.cOff[4] = 7 * Tn;
    for (int g5 = 0; g5 < 5; ++g5) {
      tg.Kg[g5] = Kg5[g5];
      tg.kch[g5] = ((Kg5[g5] / 64 + ns[g5] - 1) / ns[g5]) * 64;
      tg.ntn[g5] = 1;
      tg.Nv[g5] = Ng5[g5];
    }

    long crl = (long)(interpElems / (size_t)Kpad) & ~(long)255;
    int cr = (crl > (long)CrA[L]) ? CrA[L] : (int)crl;
    if (cr < 256) cr = 256;
    for (int v0 = 0; v0 < V_PAD; v0 += cr) {
      int rows = imin(cr, V_PAD - v0);
      int nv = imin(rows, V_N - v0);
      { int total = nv * 5 * C8;
        interp_fft_kernel<<<dim3((total + 255) / 256), dim3(256), 0, stream>>>(
            cursig, Cc, C8, bc_idx, bc_w, interp, v0, Kpad, K0pad, K1, total); }
      int ntm = rows / 256;
      tg.start[0] = 0;
      for (int g5 = 0; g5 < 5; ++g5) tg.start[g5 + 1] = tg.start[g5] + ns[g5] * ntm;
      gemm_grp<<<dim3(tg.start[5]), dim3(512), 0, stream>>>(
          interp, Kpad, trot, gemmC + (size_t)v0 * N, N, cstride, nullptr, nv, ntm, 5, tg);
    }
    { int total = V_N * Tn;
      int ldo = (L == 2) ? 256 : ((L == 0) ? 96 : 128);
      amp_fft<<<dim3((total + 255) / 256), dim3(256), 0, stream>>>(
          gemmC, cstride, tb[L], outs[L], Tn, ldo, (L == 2) ? 1 : 0,
          ns[0], ns[1], ns[2], ns[3], ns[4], total); }
    cursig = outs[L];
  }

  { int total = V_PAD * 128;
    wdt_kernel<<<dim3((total + 255) / 256), dim3(256), 0, stream>>>(Wd, trot, total); }
  GTab td;
  td.start[0] = 0; td.start[1] = 27 * 27;
  td.aOff[0] = 0; td.bOff[0] = 0; td.cOff[0] = 0;
  td.Kg[0] = 256; td.kch[0] = 256; td.ntn[0] = 27; td.Nv[0] = V_N;
  for (int g5 = 1; g5 < 5; ++g5) { td.start[g5 + 1] = td.start[1]; td.aOff[g5] = 0; td.bOff[g5] = 0;
    td.cOff[g5] = 0; td.Kg[g5] = 256; td.kch[g5] = 256; td.ntn[g5] = 1; td.Nv[g5] = 0; }
  gemm_grp<<<dim3(27 * 27), dim3(512), 0, stream>>>(
      outL2, 256, trot, outp, V_N, 0, bd, V_N, 27, 1, td);
}

// Round 10
// 563.889 us; speedup vs baseline: 6.7777x; 1.1311x over previous
//
#include <hip/hip_runtime.h>

typedef unsigned short u16;
typedef unsigned int   u32;
typedef __bf16 bf16x8 __attribute__((ext_vector_type(8)));
typedef float  f32x4  __attribute__((ext_vector_type(4)));
typedef u32    u32x4  __attribute__((ext_vector_type(4)));
typedef u32    u32x2  __attribute__((ext_vector_type(2)));
typedef u16    u16x4  __attribute__((ext_vector_type(4)));

#define V_N   6890
#define V_PAD 6912
#define SQ2H  0.70710678118654752f

__device__ __forceinline__ float bf2f(u32 h) {
  union { u32 u; float f; } c; c.u = h << 16; return c.f;
}
__device__ __forceinline__ u16 f2bf(float f) {
  union { float f; u32 u; } c; c.f = f;
  return (u16)((c.u + 0x7fffu + ((c.u >> 16) & 1u)) >> 16);
}
__device__ __forceinline__ u32 pk(float lo, float hi) {
  return (u32)f2bf(lo) | ((u32)f2bf(hi) << 16);
}
__device__ __forceinline__ void gload_lds16(const void* g, void* l) {
  __builtin_amdgcn_global_load_lds((const __attribute__((address_space(1))) void*)g,
                                   (__attribute__((address_space(3))) void*)l, 16, 0, 0);
}

// rfft8: X[k] = sum_a x[a] e^{-2pi i k a/8}; returns Z0, (Re,Im) k=1..3, Z4.
__device__ __forceinline__ void rfft8(const float* x, float& Z0, float& Re1, float& Im1,
                                      float& Re2, float& Im2, float& Re3, float& Im3, float& Z4) {
  float s04 = x[0] + x[4], d04 = x[0] - x[4];
  float s26 = x[2] + x[6], d26 = x[2] - x[6];
  float s15 = x[1] + x[5], d15 = x[1] - x[5];
  float s37 = x[3] + x[7], d37 = x[3] - x[7];
  float e = s04 + s26, f = s15 + s37;
  Z0 = e + f; Z4 = e - f;
  Re2 = s04 - s26; Im2 = s37 - s15;
  float t1 = SQ2H * (d15 - d37), t2 = SQ2H * (d15 + d37);
  Re1 = d04 + t1; Re3 = d04 - t1;
  Im1 = -(t2 + d26); Im3 = d26 - t2;
}

// ---- f32 -> bf16 (vec4) ----
__global__ void cvt_kernel(const float* __restrict__ in, u16* __restrict__ out, int total4) {
  int g = blockIdx.x * 256 + threadIdx.x;
  if (g >= total4) return;
  f32x4 v = *(const f32x4*)(in + (size_t)g * 4);
  u16x4 o; o.x = f2bf(v.x); o.y = f2bf(v.y); o.z = f2bf(v.z); o.w = f2bf(v.w);
  *(u16x4*)(out + (size_t)g * 4) = o;
}

// ---- template FFT: build frequency-domain B groups (B0|B1|B2|B3|B4), scaled 1/8 (bins 1-3: 1/4);
//      tail threads zero the K-pad columns of B0/B4 (fused bpad). ----
__global__ void trot_fft_kernel(const float* __restrict__ T, u16* __restrict__ B,
                                int Tn, int Cc, int C4, int K0pad, int K1, int total, int pad) {
  int g = blockIdx.x * 256 + threadIdx.x;
  if (g >= total) {
    int g2 = g - total;
    int padTot = Tn * pad;
    if (g2 >= padTot) return;
    int p = g2 % pad; int t = g2 / pad;
    size_t b4off = (size_t)Tn * K0pad + (size_t)6 * Tn * K1;
    size_t o = (size_t)t * K0pad + (K0pad - pad) + p;
    B[o] = 0; B[b4off + o] = 0;
    return;
  }
  int c4 = g % C4; int q = g / C4;
  int r = q % 5; int t = q / 5;
  float hs[8][4];
#pragma unroll
  for (int a = 0; a < 8; ++a) {
    f32x4 va = *(const f32x4*)(T + ((size_t)((t * 5 + r) * 8 + a)) * Cc + c4 * 4);
#pragma unroll
    for (int j = 0; j < 4; ++j) hs[a][j] = va[j];
  }
  float Z0[4], Z4[4], Re[3][4], Im[3][4];
#pragma unroll
  for (int ch = 0; ch < 4; ++ch) {
    float x[8];
#pragma unroll
    for (int a = 0; a < 8; ++a) x[a] = hs[a][ch];
    float z0, r1, i1, r2, i2, r3, i3, z4;
    rfft8(x, z0, r1, i1, r2, i2, r3, i3, z4);
    Z0[ch] = z0 * 0.125f; Z4[ch] = z4 * 0.125f;
    Re[0][ch] = r1 * 0.25f; Im[0][ch] = i1 * 0.25f;
    Re[1][ch] = r2 * 0.25f; Im[1][ch] = i2 * 0.25f;
    Re[2][ch] = r3 * 0.25f; Im[2][ch] = i3 * 0.25f;
  }
  int cb = c4 * 4;
  u32x2 w0v; w0v[0] = pk(Z0[0], Z0[1]); w0v[1] = pk(Z0[2], Z0[3]);
  *(u32x2*)(B + (size_t)t * K0pad + r * Cc + cb) = w0v;
  size_t bo1 = (size_t)Tn * K0pad;
  size_t binSz = (size_t)2 * Tn * K1;
  int off = ((r * Cc + cb) << 1);
#pragma unroll
  for (int k = 0; k < 3; ++k) {
    u32x4 wr, wi;
#pragma unroll
    for (int j = 0; j < 4; ++j) {
      wr[j] = pk(Re[k][j], Im[k][j]);
      wi[j] = pk(-Im[k][j], Re[k][j]);
    }
    *(u32x4*)(B + bo1 + k * binSz + (size_t)t * K1 + off) = wr;
    *(u32x4*)(B + bo1 + k * binSz + (size_t)(Tn + t) * K1 + off) = wi;
  }
  u32x2 w4v; w4v[0] = pk(Z4[0], Z4[1]); w4v[1] = pk(Z4[2], Z4[3]);
  *(u32x2*)(B + bo1 + 3 * binSz + (size_t)t * K0pad + r * Cc + cb) = w4v;
}

// ---- barycentric gather + interp + rfft8 over angular axis; writes A_hat sections ----
__global__ void interp_fft_kernel(const u16* __restrict__ sig, int Cc, int C8,
                                  const int* __restrict__ idx, const float* __restrict__ wgt,
                                  u16* __restrict__ out, int v0, int Kpad, int K0pad, int K1,
                                  int total) {
  int g = blockIdx.x * 256 + threadIdx.x;
  if (g >= total) return;
  int c8 = g % C8; int q = g / C8;
  int r = q % 5; int vr = q / 5;
  size_t ib = ((size_t)((v0 + vr) * 5 + r)) * 24;
  float xs[8][8];
#pragma unroll
  for (int a = 0; a < 8; ++a) {
    int i0 = idx[ib + a * 3], i1 = idx[ib + a * 3 + 1], i2 = idx[ib + a * 3 + 2];
    float w0 = wgt[ib + a * 3], w1 = wgt[ib + a * 3 + 1], w2 = wgt[ib + a * 3 + 2];
    u32x4 s0 = *(const u32x4*)(sig + (size_t)i0 * Cc + c8 * 8);
    u32x4 s1 = *(const u32x4*)(sig + (size_t)i1 * Cc + c8 * 8);
    u32x4 s2 = *(const u32x4*)(sig + (size_t)i2 * Cc + c8 * 8);
#pragma unroll
    for (int j = 0; j < 4; ++j) {
      xs[a][2 * j]     = w0 * bf2f(s0[j] & 0xffffu) + w1 * bf2f(s1[j] & 0xffffu) + w2 * bf2f(s2[j] & 0xffffu);
      xs[a][2 * j + 1] = w0 * bf2f(s0[j] >> 16)     + w1 * bf2f(s1[j] >> 16)     + w2 * bf2f(s2[j] >> 16);
    }
  }
  float Z0[8], Z4[8], Re1[8], Im1[8], Re2[8], Im2[8], Re3[8], Im3[8];
#pragma unroll
  for (int ch = 0; ch < 8; ++ch) {
    float x[8];
#pragma unroll
    for (int a = 0; a < 8; ++a) x[a] = xs[a][ch];
    rfft8(x, Z0[ch], Re1[ch], Im1[ch], Re2[ch], Im2[ch], Re3[ch], Im3[ch], Z4[ch]);
  }
  size_t rowb = (size_t)vr * Kpad;
  int cb = c8 * 8;
  u32x4 a0, a4;
#pragma unroll
  for (int p = 0; p < 4; ++p) {
    a0[p] = pk(Z0[2 * p], Z0[2 * p + 1]);
    a4[p] = pk(Z4[2 * p], Z4[2 * p + 1]);
  }
  *(u32x4*)(out + rowb + r * Cc + cb) = a0;
  *(u32x4*)(out + rowb + K0pad + 3 * K1 + r * Cc + cb) = a4;
  int off1 = K0pad + ((r * Cc + cb) << 1);
  u32x4 wa, wb;
#pragma unroll
  for (int j = 0; j < 4; ++j) { wa[j] = pk(Re1[j], Im1[j]); wb[j] = pk(Re1[4 + j], Im1[4 + j]); }
  *(u32x4*)(out + rowb + off1) = wa;
  *(u32x4*)(out + rowb + off1 + 8) = wb;
#pragma unroll
  for (int j = 0; j < 4; ++j) { wa[j] = pk(Re2[j], Im2[j]); wb[j] = pk(Re2[4 + j], Im2[4 + j]); }
  *(u32x4*)(out + rowb + off1 + K1) = wa;
  *(u32x4*)(out + rowb + off1 + K1 + 8) = wb;
#pragma unroll
  for (int j = 0; j < 4; ++j) { wa[j] = pk(Re3[j], Im3[j]); wb[j] = pk(Re3[4 + j], Im3[4 + j]); }
  *(u32x4*)(out + rowb + off1 + 2 * K1) = wa;
  *(u32x4*)(out + rowb + off1 + 2 * K1 + 8) = wb;
}

// ---- split-K reduce + 8-point iFFT + relu(+bias) + angular max; optional split-bf16 out ----
__global__ void amp_fft(const float* __restrict__ Cin, size_t cstride,
                        const float* __restrict__ bias, u16* __restrict__ out,
                        int Tn, int ldo, int split,
                        int ns0, int ns1, int ns2, int ns3, int ns4, int total) {
  int g = blockIdx.x * 256 + threadIdx.x;
  if (g >= total) return;
  int t = g % Tn, v = g / Tn;
  const int nsA[8] = {ns0, ns1, ns1, ns2, ns2, ns3, ns3, ns4};
  float sec[8];
  size_t base = (size_t)v * (8 * Tn) + t;
#pragma unroll
  for (int s = 0; s < 8; ++s) {
    const float* p = Cin + base + s * Tn;
    float a = p[0];
    for (int k = 1; k < nsA[s]; ++k) a += p[(size_t)k * cstride];
    sec[s] = a;
  }
  const float Ct[8] = {1.f, SQ2H, 0.f, -SQ2H, -1.f, -SQ2H, 0.f, SQ2H};
  const float St[8] = {0.f, SQ2H, 1.f, SQ2H, 0.f, -SQ2H, -1.f, -SQ2H};
  float m;
#pragma unroll
  for (int o = 0; o < 8; ++o) {
    float val = sec[0] + ((o & 1) ? -sec[7] : sec[7])
      + sec[1] * Ct[o]           - sec[2] * St[o]
      + sec[3] * Ct[(2 * o) & 7] - sec[4] * St[(2 * o) & 7]
      + sec[5] * Ct[(3 * o) & 7] - sec[6] * St[(3 * o) & 7];
    m = (o == 0) ? val : fmaxf(m, val);
  }
  m = fmaxf(m + bias[t], 0.f);
  u16 hi = f2bf(m);
  out[(size_t)v * ldo + t] = hi;
  if (split) out[(size_t)v * ldo + Tn + t] = f2bf(m - bf2f(hi));
}

// ---- Wd [128][V] f32 -> WdT split-bf16 [V_PAD][256] (hi | lo along k) ----
__global__ void wdt_kernel(const float* __restrict__ Wd, u16* __restrict__ out, int total) {
  int g = blockIdx.x * 256 + threadIdx.x;
  if (g >= total) return;
  int k = g & 127, n = g >> 7;
  float v = (n < V_N) ? Wd[(size_t)k * V_N + n] : 0.f;
  u16 hi = f2bf(v);
  out[(size_t)n * 256 + k] = hi;
  out[(size_t)n * 256 + 128 + k] = f2bf(v - bf2f(hi));
}

// ---- grouped 256-row bf16 GEMM (R7-proven schedule). Per-group nh flag:
//      nh=0: 256-wide tile (2Mx4N waves, 64 MFMA/Ktile, stage 8, vmcnt(8))
//      nh=1: 128-wide tile (4Mx2N waves, 32 MFMA/Ktile, stage 6, vmcnt(6))
//      — halves MFMA work for narrow (N<=128) frequency bins. ----
struct GTab {
  int start[6];
  int aOff[5];
  int bOff[5];
  int cOff[5];
  int Kg[5];
  int kch[5];
  int ntn[5];
  int Nv[5];
  int nh[5];
};

__global__ __launch_bounds__(512, 2) void gemm_grp(
    const u16* __restrict__ A, int lda, const u16* __restrict__ Bbase,
    float* __restrict__ C, int ldc, size_t cstride,
    const float* __restrict__ bias, int Mvalid, int ntm, int nG, GTab tb) {
  __shared__ __align__(16) u16 lA[2][256 * 64];
  __shared__ __align__(16) u16 lB[2][256 * 64];
  const int tid = threadIdx.x;
  const int w = tid >> 6, l = tid & 63;

  const int nb = gridDim.x, bid = blockIdx.x;
  const int qq = nb >> 3, rr = nb & 7;
  const int xcd = bid & 7, ii = bid >> 3;
  const int vb = (xcd < rr ? xcd * (qq + 1) : rr * (qq + 1) + (xcd - rr) * qq) + ii;

  int gI = 0;
#pragma unroll
  for (int k = 1; k < 5; ++k) if (k < nG && vb >= tb.start[k]) gI = k;
  const int local = vb - tb.start[gI];
  const int ntnG = tb.ntn[gI];
  const int per = ntm * ntnG;
  const int s = local / per;
  const int rem = local - s * per;
  const int tm = rem / ntnG, tn = rem - tm * ntnG;
  const int Kg = tb.Kg[gI];
  const int kb = s * tb.kch[gI];
  int ke = kb + tb.kch[gI]; if (ke > Kg) ke = Kg;
  const int nt = (ke - kb + 63) >> 6;
  const int Nv = tb.Nv[gI];
  const int cO = tb.cOff[gI];
  const int nh = tb.nh[gI];
  const int ldb = Kg;
  float* Cb = C + (size_t)s * cstride;

  const u16* Ab = A + (size_t)(tm * 256) * lda + tb.aOff[gI] + kb;
  const u16* Bb = Bbase + tb.bOff[gI] + (size_t)(tn * (nh ? 128 : 256)) * ldb + kb;

  const int srow = tid >> 3;
  const int scol = (((l & 7) ^ (srow & 7)) << 3);
  u16* laBase = &lA[0][0];
  u16* lbBase = &lB[0][0];

  f32x4 acc[8][4];
#pragma unroll
  for (int i = 0; i < 8; ++i)
#pragma unroll
    for (int j = 0; j < 4; ++j) acc[i][j] = (f32x4){0.f, 0.f, 0.f, 0.f};

  const int ksel = l >> 4, swz = l & 7;
  const int kc0 = ((ksel ^ swz) << 3);
  const int kc1 = (((4 + ksel) ^ swz) << 3);

  if (nh) {
    // ---------------- narrow: 128-wide tile, 4Mx2N waves ----------------
    const int wm = w >> 1, wn = w & 1;
    const int aoffbase = (wm * 64 + (l & 15)) * 64;
    const int boffbase = (wn * 64 + (l & 15)) * 64;
    auto STAGE = [&](int buf, int k0) {
      const u16* ga = Ab + (size_t)srow * lda + k0 + scol;
      const u16* gb = Bb + (size_t)srow * ldb + k0 + scol;
      u16* la = laBase + buf * (256 * 64) + w * 512;
      u16* lb = lbBase + buf * (256 * 64) + w * 512;
#pragma unroll
      for (int i = 0; i < 4; ++i)
        gload_lds16(ga + (size_t)(i * 64) * lda, la + i * 4096);
#pragma unroll
      for (int i = 0; i < 2; ++i)
        gload_lds16(gb + (size_t)(i * 64) * ldb, lb + i * 4096);
    };
    STAGE(0, 0);
    int cur = 0;
    for (int t = 0; t < nt; ++t) {
      if (t + 1 < nt) STAGE(cur ^ 1, (t + 1) * 64);
      __builtin_amdgcn_sched_barrier(0);
      if (t + 1 < nt) { asm volatile("s_waitcnt vmcnt(6)" ::: "memory"); }
      else            { asm volatile("s_waitcnt vmcnt(0)" ::: "memory"); }
      __builtin_amdgcn_s_barrier();
      __builtin_amdgcn_sched_barrier(0);
      const u16* lab = laBase + cur * (256 * 64);
      const u16* lbb = lbBase + cur * (256 * 64);
#pragma unroll
      for (int kk = 0; kk < 2; ++kk) {
        const int kc = kk ? kc1 : kc0;
        bf16x8 bfr[4];
#pragma unroll
        for (int ni = 0; ni < 4; ++ni)
          bfr[ni] = *(const bf16x8*)&lbb[boffbase + ni * 1024 + kc];
        bf16x8 afr[4];
#pragma unroll
        for (int mi = 0; mi < 4; ++mi)
          afr[mi] = *(const bf16x8*)&lab[aoffbase + mi * 1024 + kc];
        __builtin_amdgcn_s_setprio(1);
#pragma unroll
        for (int mi = 0; mi < 4; ++mi)
#pragma unroll
          for (int ni = 0; ni < 4; ++ni)
            acc[mi][ni] =
                __builtin_amdgcn_mfma_f32_16x16x32_bf16(afr[mi], bfr[ni], acc[mi][ni], 0, 0, 0);
        __builtin_amdgcn_s_setprio(0);
      }
      __builtin_amdgcn_sched_barrier(0);
      __builtin_amdgcn_s_barrier();
      cur ^= 1;
    }
    const int row0 = tm * 256 + wm * 64 + ((l >> 4) << 2);
    const int col0 = tn * 128 + wn * 64 + (l & 15);
#pragma unroll
    for (int mi = 0; mi < 4; ++mi) {
#pragma unroll
      for (int j = 0; j < 4; ++j) {
        int grow = row0 + mi * 16 + j;
        if (grow < Mvalid) {
#pragma unroll
          for (int ni = 0; ni < 4; ++ni) {
            int gcol = col0 + ni * 16;
            if (gcol < Nv) {
              float vv = acc[mi][ni][j];
              int gc = cO + gcol;
              if (bias) vv += bias[gc];
              Cb[(size_t)grow * ldc + gc] = vv;
            }
          }
        }
      }
    }
  } else {
    // ---------------- wide: 256-wide tile, 2Mx4N waves ----------------
    const int wm = w >> 2, wn = w & 3;
    const int aoffbase = (wm * 128 + (l & 15)) * 64;
    const int boffbase = (wn * 64 + (l & 15)) * 64;
    auto STAGE = [&](int buf, int k0) {
      const u16* ga = Ab + (size_t)srow * lda + k0 + scol;
      const u16* gb = Bb + (size_t)srow * ldb + k0 + scol;
      u16* la = laBase + buf * (256 * 64) + w * 512;
      u16* lb = lbBase + buf * (256 * 64) + w * 512;
#pragma unroll
      for (int i = 0; i < 4; ++i) {
        gload_lds16(ga + (size_t)(i * 64) * lda, la + i * 4096);
        gload_lds16(gb + (size_t)(i * 64) * ldb, lb + i * 4096);
      }
    };
    STAGE(0, 0);
    int cur = 0;
    for (int t = 0; t < nt; ++t) {
      if (t + 1 < nt) STAGE(cur ^ 1, (t + 1) * 64);
      __builtin_amdgcn_sched_barrier(0);
      if (t + 1 < nt) { asm volatile("s_waitcnt vmcnt(8)" ::: "memory"); }
      else            { asm volatile("s_waitcnt vmcnt(0)" ::: "memory"); }
      __builtin_amdgcn_s_barrier();
      __builtin_amdgcn_sched_barrier(0);
      const u16* lab = laBase + cur * (256 * 64);
      const u16* lbb = lbBase + cur * (256 * 64);
#pragma unroll
      for (int kk = 0; kk < 2; ++kk) {
        const int kc = kk ? kc1 : kc0;
        bf16x8 bfr[4];
#pragma unroll
        for (int ni = 0; ni < 4; ++ni)
          bfr[ni] = *(const bf16x8*)&lbb[boffbase + ni * 1024 + kc];
#pragma unroll
        for (int mh = 0; mh < 2; ++mh) {
          bf16x8 afr[4];
#pragma unroll
          for (int mi = 0; mi < 4; ++mi)
            afr[mi] = *(const bf16x8*)&lab[aoffbase + (mh * 4 + mi) * 1024 + kc];
          __builtin_amdgcn_s_setprio(1);
#pragma unroll
          for (int mi = 0; mi < 4; ++mi)
#pragma unroll
            for (int ni = 0; ni < 4; ++ni)
              acc[mh * 4 + mi][ni] =
                  __builtin_amdgcn_mfma_f32_16x16x32_bf16(afr[mi], bfr[ni], acc[mh * 4 + mi][ni], 0, 0, 0);
          __builtin_amdgcn_s_setprio(0);
        }
      }
      __builtin_amdgcn_sched_barrier(0);
      __builtin_amdgcn_s_barrier();
      cur ^= 1;
    }
    const int row0 = tm * 256 + wm * 128 + ((l >> 4) << 2);
    const int col0 = tn * 256 + wn * 64 + (l & 15);
#pragma unroll
    for (int mi = 0; mi < 8; ++mi) {
#pragma unroll
      for (int j = 0; j < 4; ++j) {
        int grow = row0 + mi * 16 + j;
        if (grow < Mvalid) {
#pragma unroll
          for (int ni = 0; ni < 4; ++ni) {
            int gcol = col0 + ni * 16;
            if (gcol < Nv) {
              float vv = acc[mi][ni][j];
              int gc = cO + gcol;
              if (bias) vv += bias[gc];
              Cb[(size_t)grow * ldc + gc] = vv;
            }
          }
        }
      }
    }
  }
}

static inline int imin(int a, int b) { return a < b ? a : b; }

extern "C" void kernel_launch(void* const* d_in, const int* in_sizes, int n_in,
                              void* d_out, int out_size, void* d_ws, size_t ws_size,
                              hipStream_t stream) {
  const float* signal = (const float*)d_in[0];
  const int*   bc_idx = (const int*)d_in[1];
  const float* bc_w   = (const float*)d_in[2];
  const float* tmpl[3] = { (const float*)d_in[3], (const float*)d_in[5], (const float*)d_in[7] };
  const float* tb[3]   = { (const float*)d_in[4], (const float*)d_in[6], (const float*)d_in[8] };
  const float* Wd = (const float*)d_in[9];
  const float* bd = (const float*)d_in[10];
  float* outp = (float*)d_out;

  char* ws = (char*)d_ws;
  size_t off = 0;
  auto alloc = [&](size_t b) -> void* {
    size_t o = (off + 255) & ~(size_t)255; off = o + b; return (void*)(ws + o);
  };
  u16* sigbf = (u16*)alloc((size_t)V_N * 544 * 2);
  u16* outL0 = (u16*)alloc((size_t)V_PAD * 96 * 2);
  u16* outL1 = (u16*)alloc((size_t)V_PAD * 128 * 2);
  u16* outL2 = (u16*)alloc((size_t)V_PAD * 256 * 2);       // split hi|lo
  u16* trot  = (u16*)alloc((size_t)8 * 1024 * 1024 * 2);   // B_hat (max 7.3MB) / WdT; +margin
  float* gemmC = (float*)alloc((size_t)4 * V_PAD * 1024 * 4); // split-K partials
  size_t o2 = (off + 255) & ~(size_t)255;
  u16* interp = (u16*)(ws + o2);
  size_t interpElems = (ws_size > o2) ? (ws_size - o2) / 2 : 0;

  { int total4 = V_N * 544 / 4;
    cvt_kernel<<<dim3((total4 + 255) / 256), dim3(256), 0, stream>>>(signal, sigbf, total4); }

  const int TnA[3] = {96, 128, 128}, CcA[3] = {544, 96, 128};
  const int nsTab[3][5] = {{2,5,5,4,2},{1,2,2,2,1},{1,2,2,2,1}};
  const int CrA[3] = {3584, V_PAD, V_PAD};
  u16* outs[3] = { outL0, outL1, outL2 };
  const u16* cursig = sigbf;
  for (int L = 0; L < 3; ++L) {
    const int Tn = TnA[L], Cc = CcA[L];
    const int C8 = Cc / 8, C4 = Cc / 4;
    const int K0 = 5 * Cc, K0pad = ((K0 + 63) / 64) * 64;
    const int K1 = 10 * Cc;
    const int Kpad = 2 * K0pad + 3 * K1;
    const int N = 8 * Tn;
    const int* ns = nsTab[L];
    const size_t cstride = (size_t)V_PAD * N;
    const int pad = K0pad - K0;

    { int total = Tn * 5 * C4;
      int total2 = total + Tn * pad;
      trot_fft_kernel<<<dim3((total2 + 255) / 256), dim3(256), 0, stream>>>(
          tmpl[L], trot, Tn, Cc, C4, K0pad, K1, total, pad); }

    GTab tg;
    int Kg5[5] = {K0pad, K1, K1, K1, K0pad};
    int Ng5[5] = {Tn, 2 * Tn, 2 * Tn, 2 * Tn, Tn};
    tg.aOff[0] = 0; tg.aOff[1] = K0pad; tg.aOff[2] = K0pad + K1;
    tg.aOff[3] = K0pad + 2 * K1; tg.aOff[4] = K0pad + 3 * K1;
    tg.bOff[0] = 0; tg.bOff[1] = Tn * K0pad;
    tg.bOff[2] = Tn * K0pad + 2 * Tn * K1;
    tg.bOff[3] = Tn * K0pad + 4 * Tn * K1;
    tg.bOff[4] = Tn * K0pad + 6 * Tn * K1;
    tg.cOff[0] = 0; tg.cOff[1] = Tn; tg.cOff[2] = 3 * Tn; tg.cOff[3] = 5 * Tn; tg.cOff[4] = 7 * Tn;
    for (int g5 = 0; g5 < 5; ++g5) {
      tg.Kg[g5] = Kg5[g5];
      tg.kch[g5] = ((Kg5[g5] / 64 + ns[g5] - 1) / ns[g5]) * 64;
      tg.ntn[g5] = 1;
      tg.Nv[g5] = Ng5[g5];
      tg.nh[g5] = (g5 == 0 || g5 == 4) ? 1 : 0;   // DC/Nyquist bins: N<=128 -> narrow tile
    }

    long crl = (long)(interpElems / (size_t)Kpad) & ~(long)255;
    int cr = (crl > (long)CrA[L]) ? CrA[L] : (int)crl;
    if (cr < 256) cr = 256;
    for (int v0 = 0; v0 < V_PAD; v0 += cr) {
      int rows = imin(cr, V_PAD - v0);
      int nv = imin(rows, V_N - v0);
      { int total = nv * 5 * C8;
        interp_fft_kernel<<<dim3((total + 255) / 256), dim3(256), 0, stream>>>(
            cursig, Cc, C8, bc_idx, bc_w, interp, v0, Kpad, K0pad, K1, total); }
      int ntm = rows / 256;
      tg.start[0] = 0;
      for (int g5 = 0; g5 < 5; ++g5) tg.start[g5 + 1] = tg.start[g5] + ns[g5] * ntm;
      gemm_grp<<<dim3(tg.start[5]), dim3(512), 0, stream>>>(
          interp, Kpad, trot, gemmC + (size_t)v0 * N, N, cstride, nullptr, nv, ntm, 5, tg);
    }
    { int total = V_N * Tn;
      int ldo = (L == 2) ? 256 : ((L == 0) ? 96 : 128);
      amp_fft<<<dim3((total + 255) / 256), dim3(256), 0, stream>>>(
          gemmC, cstride, tb[L], outs[L], Tn, ldo, (L == 2) ? 1 : 0,
          ns[0], ns[1], ns[2], ns[3], ns[4], total); }
    cursig = outs[L];
  }

  { int total = V_PAD * 128;
    wdt_kernel<<<dim3((total + 255) / 256), dim3(256), 0, stream>>>(Wd, trot, total); }
  GTab td;
  td.start[0] = 0; td.start[1] = 27 * 27;
  td.aOff[0] = 0; td.bOff[0] = 0; td.cOff[0] = 0;
  td.Kg[0] = 256; td.kch[0] = 256; td.ntn[0] = 27; td.Nv[0] = V_N; td.nh[0] = 0;
  for (int g5 = 1; g5 < 5; ++g5) { td.start[g5 + 1] = td.start[1]; td.aOff[g5] = 0; td.bOff[g5] = 0;
    td.cOff[g5] = 0; td.Kg[g5] = 256; td.kch[g5] = 256; td.ntn[g5] = 1; td.Nv[g5] = 0; td.nh[g5] = 0; }
  gemm_grp<<<dim3(27 * 27), dim3(512), 0, stream>>>(
      outL2, 256, trot, outp, V_N, 0, bd, V_N, 27, 1, td);
}